// Round 13
// baseline (385.279 us; speedup 1.0000x reference)
//
#include <hip/hip_runtime.h>
#include <math.h>

#define BB 4
#define CC 128
#define HH 48
#define WW 48
#define NSP (HH*WW)          // 2304
#define DCC 256
#define BCN (BB*CC*NSP)      // 1179648
#define KS 4                 // attention key-splits

typedef float f32x4 __attribute__((ext_vector_type(4)));
typedef __bf16 bf16x8 __attribute__((ext_vector_type(8)));
typedef __bf16 bf16x4 __attribute__((ext_vector_type(4)));

__device__ __forceinline__ float sigmf(float v) { return 1.0f / (1.0f + __expf(-v)); }

// ---------------- merged prep: weight cvt (13) + conv3x3 pack (4) + x-stats + x dual-transpose ----------------
struct Prep {
  const float* wsrc[13];
  int wlen[13];
  int woff[13];
  const float* psrc[4];
  int pcin[4];
  int poff[4];
  const float* x;
  float* sums;
  float* sums2;
  __bf16* x_t;
  __bf16* xrope_t;
};
__global__ __launch_bounds__(256) void prep_kernel(Prep a, __bf16* __restrict__ wdst,
                                                   __bf16* __restrict__ pdst) {
  __shared__ float lds[32][33];
  __shared__ float rs[4], rs2[4];
  int g = blockIdx.y;
  int idx = blockIdx.x * 256 + threadIdx.x;
  if (g < 13) {
    if (idx < a.wlen[g]) wdst[a.woff[g] + idx] = (__bf16)a.wsrc[g][idx];
  } else if (g < 17) {
    int L = g - 13;
    int cin = a.pcin[L];
    if (idx < 9 * 32 * cin) {
      int c = idx % cin;
      int o = (idx / cin) % 32;
      int tap = idx / (cin * 32);
      pdst[a.poff[L] + idx] = (__bf16)a.psrc[L][((size_t)o * cin + c) * 9 + tap];
    }
  } else if (g == 17) {
    // x-channel BN stats: one block per channel (plain stores, no atomics)
    int c = blockIdx.x;
    if (c >= 128) return;
    float s = 0.f, s2 = 0.f;
    for (int i = threadIdx.x; i < BB * NSP; i += 256) {
      int b = i / NSP, n = i % NSP;
      float v = a.x[((size_t)b * 128 + c) * NSP + n];
      s += v;
      s2 += v * v;
    }
#pragma unroll
    for (int off = 32; off > 0; off >>= 1) {
      s += __shfl_down(s, off);
      s2 += __shfl_down(s2, off);
    }
    int wid = threadIdx.x >> 6;
    if ((threadIdx.x & 63) == 0) { rs[wid] = s; rs2[wid] = s2; }
    __syncthreads();
    if (threadIdx.x == 0) {
      a.sums[c] = rs[0] + rs[1] + rs[2] + rs[3];
      a.sums2[c] = rs2[0] + rs2[1] + rs2[2] + rs2[3];
    }
  } else {
    // dual transpose x -> x_t (plain) + xrope_t (RoPE), LDS-tiled
    int T = (g - 18) * 256 + blockIdx.x;
    if (T >= 1152) return;
    int b = T / 288;
    int r = T % 288;
    int c0 = (r / 72) * 32;
    int n0 = (r % 72) * 32;
    int tid = threadIdx.x;
    int nn = tid & 31, cs = tid >> 5;
#pragma unroll
    for (int j = 0; j < 4; ++j) {
      int cc = c0 + cs * 4 + j;
      lds[cs * 4 + j][nn] = a.x[((size_t)b * 128 + cc) * NSP + n0 + nn];
    }
    __syncthreads();
    int c = tid & 31, ns = tid >> 5;
#pragma unroll
    for (int j = 0; j < 4; ++j) {
      int n2 = ns * 4 + j;
      float pv = lds[c][n2];
      a.x_t[((size_t)b * NSP + n0 + n2) * 128 + c0 + c] = (__bf16)pv;
      int gc = c0 + c;
      int i = gc >> 1;
      float re = lds[c & ~1][n2];
      float im = lds[c | 1][n2];
      int n = n0 + n2;
      int h = n / WW, w = n % WW;
      float theta = __expf(-9.2103403719761836f * ((float)i) / 64.0f);
      float pos = (float)(h + w) * theta;
      float cs_ = cosf(pos), sn_ = sinf(pos);
      float vr_ = (gc & 1) ? (re * sn_ + im * cs_) : (re * cs_ - im * sn_);
      a.xrope_t[((size_t)b * NSP + n0 + n2) * 128 + c0 + c] = (__bf16)vr_;
    }
  }
}

// ---------------- fused k|v|r GEMM + full rwkv epilogue (no intermediate buffers) ----------------
__global__ __launch_bounds__(256) void kvr_kernel(
    const __bf16* __restrict__ xrope_t, const __bf16* __restrict__ x_t,
    const __bf16* __restrict__ wk, const __bf16* __restrict__ wvp,
    const __bf16* __restrict__ wr,
    const float* __restrict__ k_b, const float* __restrict__ v_b,
    const float* __restrict__ r_b, const float* __restrict__ u,
    float* __restrict__ kden, float* __restrict__ knum, float* __restrict__ rec) {
  int tid = threadIdx.x;
  int wv = tid >> 6, lane = tid & 63;
  int m15 = lane & 15, quad = lane >> 4;
  int b = blockIdx.y;
  int n0 = blockIdx.x * 16;
  int o0 = wv * 32;
  int n = n0 + m15;
  const __bf16* brr = xrope_t + ((size_t)b * NSP + n) * 128 + quad * 8;
  const __bf16* brx = x_t + ((size_t)b * NSP + n) * 128 + quad * 8;
  const __bf16* ak0 = wk + (size_t)(o0 + m15) * 128 + quad * 8;
  const __bf16* ak1 = wk + (size_t)(o0 + 16 + m15) * 128 + quad * 8;
  const __bf16* av0 = wvp + (size_t)(o0 + m15) * 128 + quad * 8;
  const __bf16* av1 = wvp + (size_t)(o0 + 16 + m15) * 128 + quad * 8;
  const __bf16* ar0 = wr + (size_t)(o0 + m15) * 128 + quad * 8;
  const __bf16* ar1 = wr + (size_t)(o0 + 16 + m15) * 128 + quad * 8;
  f32x4 fk[2], fv[2], fr[2];
#pragma unroll
  for (int t = 0; t < 2; ++t) {
    fk[t] = (f32x4){0.f, 0.f, 0.f, 0.f};
    fv[t] = (f32x4){0.f, 0.f, 0.f, 0.f};
    fr[t] = (f32x4){0.f, 0.f, 0.f, 0.f};
  }
#pragma unroll
  for (int kc = 0; kc < 128; kc += 32) {
    bf16x8 br_ = *(const bf16x8*)(brr + kc);
    bf16x8 bx_ = *(const bf16x8*)(brx + kc);
    fk[0] = __builtin_amdgcn_mfma_f32_16x16x32_bf16(*(const bf16x8*)(ak0 + kc), br_, fk[0], 0, 0, 0);
    fk[1] = __builtin_amdgcn_mfma_f32_16x16x32_bf16(*(const bf16x8*)(ak1 + kc), br_, fk[1], 0, 0, 0);
    fv[0] = __builtin_amdgcn_mfma_f32_16x16x32_bf16(*(const bf16x8*)(av0 + kc), br_, fv[0], 0, 0, 0);
    fv[1] = __builtin_amdgcn_mfma_f32_16x16x32_bf16(*(const bf16x8*)(av1 + kc), br_, fv[1], 0, 0, 0);
    fr[0] = __builtin_amdgcn_mfma_f32_16x16x32_bf16(*(const bf16x8*)(ar0 + kc), bx_, fr[0], 0, 0, 0);
    fr[1] = __builtin_amdgcn_mfma_f32_16x16x32_bf16(*(const bf16x8*)(ar1 + kc), bx_, fr[1], 0, 0, 0);
  }
#pragma unroll
  for (int t = 0; t < 2; ++t) {
#pragma unroll
    for (int reg = 0; reg < 4; ++reg) {
      int ol = o0 + t * 16 + quad * 4 + reg;
      float kk = fk[t][reg] + k_b[ol];
      float vv = fv[t][reg] + v_b[ol];
      float rr = sigmf(fr[t][reg] + r_b[ol]);
      float eu = __expf(u[ol]);
      size_t idx = ((size_t)b * 128 + ol) * NSP + n;
      float nv = kk * vv, tt = eu * kk;
      kden[idx] = kk;
      knum[idx] = nv;
      rec[idx] = rr * ((nv + tt * vv) / (kk + tt));
    }
  }
}

// ---------------- fused sn1+sn2: z1 kept in LDS, tau partials out ----------------
__global__ __launch_bounds__(256) void sn12_kernel(
    const __bf16* __restrict__ x_t, const __bf16* __restrict__ dense_t,
    const __bf16* __restrict__ wsn1, const float* __restrict__ sn1_b,
    const __bf16* __restrict__ wsn2, const float* __restrict__ sn2_b,
    float* __restrict__ taupart) {
  __shared__ __bf16 z1l[16][72];  // 72-pad: 2-way max bank aliasing on b128 reads
  int tid = threadIdx.x;
  int wv = tid >> 6, lane = tid & 63;
  int m15 = lane & 15, quad = lane >> 4;
  int b = blockIdx.y;
  int n0 = blockIdx.x * 16;
  int n = n0 + m15;
  if (wv < 2) {
    int o0 = wv * 32;
    const __bf16* bx = x_t + ((size_t)b * NSP + n) * 128 + quad * 8;
    const __bf16* bd = dense_t + ((size_t)b * NSP + n) * 128 + quad * 8;
    const __bf16* a0p = wsn1 + (size_t)(o0 + m15) * 256 + quad * 8;
    const __bf16* a1p = wsn1 + (size_t)(o0 + 16 + m15) * 256 + quad * 8;
    f32x4 of0 = (f32x4){0.f, 0.f, 0.f, 0.f};
    f32x4 of1 = (f32x4){0.f, 0.f, 0.f, 0.f};
#pragma unroll
    for (int kc = 0; kc < 256; kc += 32) {
      bf16x8 bfr = (kc < 128) ? *(const bf16x8*)(bx + kc) : *(const bf16x8*)(bd + (kc - 128));
      bf16x8 a0 = *(const bf16x8*)(a0p + kc);
      bf16x8 a1 = *(const bf16x8*)(a1p + kc);
      of0 = __builtin_amdgcn_mfma_f32_16x16x32_bf16(a0, bfr, of0, 0, 0, 0);
      of1 = __builtin_amdgcn_mfma_f32_16x16x32_bf16(a1, bfr, of1, 0, 0, 0);
    }
#pragma unroll
    for (int t = 0; t < 2; ++t) {
      f32x4 acc = t ? of1 : of0;
#pragma unroll
      for (int reg = 0; reg < 4; ++reg) {
        int ol = o0 + t * 16 + quad * 4 + reg;
        z1l[m15][ol] = (__bf16)fmaxf(acc[reg] + sn1_b[ol], 0.0f);
      }
    }
  }
  __syncthreads();
  // sn2 from LDS z1 (K=64), sigmoid, per-(b,ch) tau partials
  bf16x8 bfr0 = *(const bf16x8*)&z1l[m15][quad * 8];
  bf16x8 bfr1 = *(const bf16x8*)&z1l[m15][32 + quad * 8];
#pragma unroll
  for (int ot = 0; ot < 2; ++ot) {
    int o0 = (wv * 2 + ot) * 32;
    const __bf16* a0p = wsn2 + (size_t)(o0 + m15) * 64 + quad * 8;
    const __bf16* a1p = wsn2 + (size_t)(o0 + 16 + m15) * 64 + quad * 8;
    f32x4 of0 = (f32x4){0.f, 0.f, 0.f, 0.f};
    f32x4 of1 = (f32x4){0.f, 0.f, 0.f, 0.f};
    of0 = __builtin_amdgcn_mfma_f32_16x16x32_bf16(*(const bf16x8*)(a0p), bfr0, of0, 0, 0, 0);
    of0 = __builtin_amdgcn_mfma_f32_16x16x32_bf16(*(const bf16x8*)(a0p + 32), bfr1, of0, 0, 0, 0);
    of1 = __builtin_amdgcn_mfma_f32_16x16x32_bf16(*(const bf16x8*)(a1p), bfr0, of1, 0, 0, 0);
    of1 = __builtin_amdgcn_mfma_f32_16x16x32_bf16(*(const bf16x8*)(a1p + 32), bfr1, of1, 0, 0, 0);
#pragma unroll
    for (int t = 0; t < 2; ++t) {
      f32x4 acc = t ? of1 : of0;
#pragma unroll
      for (int reg = 0; reg < 4; ++reg) {
        int ol = o0 + t * 16 + quad * 4 + reg;
        float sv = sigmf(acc[reg] + sn2_b[ol]);
        sv += __shfl_xor(sv, 1);
        sv += __shfl_xor(sv, 2);
        sv += __shfl_xor(sv, 4);
        sv += __shfl_xor(sv, 8);
        if (m15 == 0)
          taupart[((size_t)(b * DCC + ol)) * 144 + blockIdx.x] = sv;
      }
    }
  }
}

// ---------------- lb|ld GEMM with inline spike-fn B (sf never materialized) ----------------
__global__ __launch_bounds__(128) void lbld_sf_kernel(
    const __bf16* __restrict__ x_t, const __bf16* __restrict__ dense_t,
    const float* __restrict__ taupart, const __bf16* __restrict__ wlb,
    const float* __restrict__ lb_b, const float* __restrict__ ld_b,
    __bf16* __restrict__ Bft, __bf16* __restrict__ Dfb) {
  __shared__ float ef[256];  // exp(-1/(tau+eps)) - 1 per channel
  int tid = threadIdx.x;
  int b = blockIdx.y;
  for (int ch = tid; ch < 256; ch += 128) {
    const f32x4* tp = (const f32x4*)(taupart + ((size_t)(b * DCC + ch)) * 144);
    f32x4 s4 = (f32x4){0.f, 0.f, 0.f, 0.f};
#pragma unroll
    for (int j = 0; j < 36; ++j) s4 += tp[j];
    float tv = (s4.x + s4.y + s4.z + s4.w) * (1.0f / (float)NSP);
    ef[ch] = __expf(-1.0f / (tv + 1e-6f)) - 1.0f;
  }
  __syncthreads();
  int wv = tid >> 6, lane = tid & 63;
  int m15 = lane & 15, quad = lane >> 4;
  int n0 = blockIdx.x * 16;
  int o0 = wv * 32;
  int n = n0 + m15;
  const __bf16* bx = x_t + ((size_t)b * NSP + n) * 128 + quad * 8;
  const __bf16* bd = dense_t + ((size_t)b * NSP + n) * 128 + quad * 8;
  const __bf16* a0p = wlb + (size_t)(o0 + m15) * 256 + quad * 8;
  const __bf16* a1p = wlb + (size_t)(o0 + 16 + m15) * 256 + quad * 8;
  f32x4 of0 = (f32x4){0.f, 0.f, 0.f, 0.f};
  f32x4 of1 = (f32x4){0.f, 0.f, 0.f, 0.f};
#pragma unroll
  for (int kc = 0; kc < 256; kc += 32) {
    bf16x8 raw = (kc < 128) ? *(const bf16x8*)(bx + kc) : *(const bf16x8*)(bd + (kc - 128));
    bf16x8 sfv;
#pragma unroll
    for (int j = 0; j < 8; ++j) {
      float df = (float)raw[j];
      float sp = sigmf((df - 1.0f) * 5.0f);
      sfv[j] = (__bf16)(df * (1.0f + sp * ef[kc + quad * 8 + j]));
    }
    bf16x8 a0 = *(const bf16x8*)(a0p + kc);
    bf16x8 a1 = *(const bf16x8*)(a1p + kc);
    of0 = __builtin_amdgcn_mfma_f32_16x16x32_bf16(a0, sfv, of0, 0, 0, 0);
    of1 = __builtin_amdgcn_mfma_f32_16x16x32_bf16(a1, sfv, of1, 0, 0, 0);
  }
  if (o0 == 0) {  // lb -> Bft (B,N,32) transposed
#pragma unroll
    for (int t = 0; t < 2; ++t) {
      f32x4 acc = t ? of1 : of0;
      bf16x4 pk;
#pragma unroll
      for (int reg = 0; reg < 4; ++reg) pk[reg] = (__bf16)(acc[reg] + lb_b[t * 16 + quad * 4 + reg]);
      *(bf16x4*)(Bft + ((size_t)b * NSP + n) * 32 + t * 16 + quad * 4) = pk;
    }
  } else {  // ld -> Dfb (B,32,N) planar
#pragma unroll
    for (int t = 0; t < 2; ++t) {
      f32x4 acc = t ? of1 : of0;
#pragma unroll
      for (int reg = 0; reg < 4; ++reg) {
        int ol = t * 16 + quad * 4 + reg;
        Dfb[((size_t)b * 32 + ol) * NSP + n] = (__bf16)(acc[reg] + ld_b[ol]);
      }
    }
  }
}

// ---------------- conv3x3 with cached BN activations ----------------
// Channels < nold are read pre-BN'd+ReLU'd from bnrelu (B,N,256) bf16 -> zero B-path VALU.
// The newest channels ([wb0,Cin), wb0 = nold ? Cin-32 : 0) are BN'd inline AND their BN'd
// values are written to bnrelu (own 16 rows) for later layers. Bit-identical rounding.
template <int Cin>
__global__ __launch_bounds__(256) void convbn_kernel(
    const __bf16* __restrict__ x_t, const __bf16* __restrict__ dense_t,
    __bf16* __restrict__ bnrelu,
    const __bf16* __restrict__ wb, const float* __restrict__ cb,
    float* __restrict__ sums, float* __restrict__ sums2,
    const float* __restrict__ cpart_in,
    const float* __restrict__ g, const float* __restrict__ bbp,
    __bf16* __restrict__ dense_out, float* __restrict__ cpart_out,
    int cout0, int nold) {
  constexpr int KCin = Cin / 32;
  constexpr int NIT = 9 * KCin;
  __shared__ float red[4][64][8];
  __shared__ float scsh[2][Cin];
  __shared__ float tred[64][4];
  __shared__ float fin[64];
  int tid = threadIdx.x;
  const float inv = 1.0f / (float)(BB * NSP);

  if (cpart_in) {
    int row = tid >> 2, sl = tid & 3;
    const f32x4* cp = (const f32x4*)(cpart_in + (size_t)row * 576 + sl * 144);
    f32x4 s4 = (f32x4){0.f, 0.f, 0.f, 0.f};
#pragma unroll
    for (int j = 0; j < 36; ++j) s4 += cp[j];
    tred[row][sl] = s4.x + s4.y + s4.z + s4.w;
    __syncthreads();
    if (tid < 64) fin[tid] = tred[tid][0] + tred[tid][1] + tred[tid][2] + tred[tid][3];
    __syncthreads();
    if (blockIdx.x == 0 && blockIdx.y == 0 && tid < 32) {
      sums[Cin - 32 + tid] = fin[tid];
      sums2[Cin - 32 + tid] = fin[32 + tid];
    }
  }
  for (int ch = tid; ch < Cin; ch += 256) {
    float S, S2;
    if (cpart_in && ch >= Cin - 32) {
      S = fin[ch - (Cin - 32)];
      S2 = fin[ch - (Cin - 32) + 32];
    } else {
      S = sums[ch];
      S2 = sums2[ch];
    }
    float m = S * inv;
    float var = S2 * inv - m * m;
    float sc_ = rsqrtf(var + 1e-5f) * g[ch];
    scsh[0][ch] = sc_;
    scsh[1][ch] = bbp[ch] - m * sc_;
  }
  __syncthreads();

  int wv = tid >> 6, lane = tid & 63;
  int m15 = lane & 15, quad = lane >> 4;
  int b = blockIdx.y;
  int n0 = blockIdx.x * 16;
  int n = n0 + m15;
  int h = n / WW, w = n % WW;

  // write BN'd newest channels (own 16 rows) to bnrelu for later layers
  {
    int wb0 = nold ? (Cin - 32) : 0;
    int ngrp = (Cin - wb0) / 8;  // 16 (layer 0) or 4
    if (tid < 16 * ngrp) {
      int r = tid / ngrp, cg = tid % ngrp;
      int c = wb0 + cg * 8;
      int nn2 = n0 + r;
      const __bf16* srcp = (c < 128) ? (x_t + ((size_t)b * NSP + nn2) * 128 + c)
                                     : (dense_t + ((size_t)b * NSP + nn2) * 128 + (c - 128));
      bf16x8 rv = *(const bf16x8*)srcp;
      bf16x8 ov;
#pragma unroll
      for (int j = 0; j < 8; ++j)
        ov[j] = (__bf16)fmaxf((float)rv[j] * scsh[0][c + j] + scsh[1][c + j], 0.0f);
      *(bf16x8*)(bnrelu + ((size_t)b * NSP + nn2) * DCC + c) = ov;
    }
  }

  f32x4 of0 = (f32x4){0.f, 0.f, 0.f, 0.f};
  f32x4 of1 = (f32x4){0.f, 0.f, 0.f, 0.f};
  const __bf16* bx_ = x_t + (size_t)b * NSP * 128;
  const __bf16* bd_ = dense_t + (size_t)b * NSP * 128;
  const __bf16* bnr_ = bnrelu + (size_t)b * NSP * DCC;
  const bf16x8 zf = {};
  int begin = (wv * NIT) / 4, end = ((wv + 1) * NIT) / 4;
  int cur = -1;
  float bsc[8], bsh[8];
  const __bf16* base = nullptr;
  for (int ci = begin; ci < end; ++ci) {
    int chunk = ci / 9;
    int tap = ci - chunk * 9;
    int kc = chunk * 32;
    int dh = tap / 3 - 1, dw = tap % 3 - 1;
    bool valid = ((unsigned)(h + dh) < HH) && ((unsigned)(w + dw) < WW);
    int pa = valid ? (n + dh * WW + dw) : 0;
    bf16x8 bfr;
    if (kc + 32 <= nold) {
      // pre-BN'd channels: direct operand load, zero VALU
      bfr = *(const bf16x8*)(bnr_ + (size_t)pa * DCC + kc + quad * 8);
      if (!valid) bfr = zf;
    } else {
      if (chunk != cur) {
        cur = chunk;
        int cc = kc + quad * 8;
#pragma unroll
        for (int j = 0; j < 8; ++j) {
          bsc[j] = scsh[0][cc + j];
          bsh[j] = scsh[1][cc + j];
        }
        base = (cc < 128) ? (bx_ + cc) : (bd_ + cc - 128);
      }
      bf16x8 raw = *(const bf16x8*)(base + (size_t)pa * 128);
#pragma unroll
      for (int j = 0; j < 8; ++j) {
        float v = fmaxf((float)raw[j] * bsc[j] + bsh[j], 0.0f);
        bfr[j] = (__bf16)v;
      }
      if (!valid) bfr = zf;
    }
    const __bf16* wt = wb + (size_t)tap * 32 * Cin + kc + quad * 8;
    bf16x8 a0 = *(const bf16x8*)(wt + (size_t)m15 * Cin);
    bf16x8 a1 = *(const bf16x8*)(wt + (size_t)(16 + m15) * Cin);
    of0 = __builtin_amdgcn_mfma_f32_16x16x32_bf16(a0, bfr, of0, 0, 0, 0);
    of1 = __builtin_amdgcn_mfma_f32_16x16x32_bf16(a1, bfr, of1, 0, 0, 0);
  }
  float* myred = red[wv][lane];
#pragma unroll
  for (int reg = 0; reg < 4; ++reg) {
    myred[reg] = of0[reg];
    myred[4 + reg] = of1[reg];
  }
  __syncthreads();
  if (wv == 0) {
    int dloc = cout0 - 128;
    __bf16* dt = dense_out + ((size_t)b * NSP + n) * 128 + dloc;
    bf16x4 pk0, pk1;
    float sv[4][4];
#pragma unroll
    for (int reg = 0; reg < 4; ++reg) {
      int o = quad * 4 + reg;
      float v0 = red[0][lane][reg] + red[1][lane][reg] + red[2][lane][reg] +
                 red[3][lane][reg] + cb[o];
      float v1 = red[0][lane][4 + reg] + red[1][lane][4 + reg] + red[2][lane][4 + reg] +
                 red[3][lane][4 + reg] + cb[16 + o];
      pk0[reg] = (__bf16)v0;
      pk1[reg] = (__bf16)v1;
      sv[reg][0] = v0;
      sv[reg][1] = v0 * v0;
      sv[reg][2] = v1;
      sv[reg][3] = v1 * v1;
    }
    *(bf16x4*)(dt + quad * 4) = pk0;
    *(bf16x4*)(dt + 16 + quad * 4) = pk1;
    if (cpart_out) {
#pragma unroll
      for (int reg = 0; reg < 4; ++reg) {
        float a0 = sv[reg][0], q0 = sv[reg][1], a1 = sv[reg][2], q1 = sv[reg][3];
#pragma unroll
        for (int mk = 1; mk < 16; mk <<= 1) {
          a0 += __shfl_xor(a0, mk);
          q0 += __shfl_xor(q0, mk);
          a1 += __shfl_xor(a1, mk);
          q1 += __shfl_xor(q1, mk);
        }
        if (m15 == 0) {
          int o = quad * 4 + reg;
          int pidx = blockIdx.y * 144 + blockIdx.x;
          cpart_out[(size_t)o * 576 + pidx] = a0;
          cpart_out[(size_t)(32 + o) * 576 + pidx] = q0;
          cpart_out[(size_t)(16 + o) * 576 + pidx] = a1;
          cpart_out[(size_t)(48 + o) * 576 + pidx] = q1;
        }
      }
    }
  }
}

// ---------------- flash-LDS MFMA attention: swapped QK^T, transpose-free P (no pt buffer) ----------------
template <int CD>
__global__ __launch_bounds__(256) void attn_part_kernel(
    const __bf16* __restrict__ Qt, const __bf16* __restrict__ Kt,
    const __bf16* __restrict__ Vb, __bf16* __restrict__ Op,
    float* __restrict__ lp) {
  constexpr int NC = CD / 16;
  constexpr int KC = CD / 32;
  constexpr int KEYS = NSP / KS;  // 576
  constexpr int KP = CD + 4;
  constexpr int VP = 36;
  __shared__ __bf16 kl[32][KP];
  __shared__ __bf16 vl[CD][VP];
  int tid = threadIdx.x;
  int wv = tid >> 6, lane = tid & 63;
  int m15 = lane & 15, quad = lane >> 4;
  int b = blockIdx.y, ks = blockIdx.z;
  int n0 = blockIdx.x * 64 + wv * 16;

  bf16x8 qf[KC];
  const __bf16* qrow = Qt + ((size_t)b * NSP + n0 + m15) * CD + quad * 8;
#pragma unroll
  for (int kc = 0; kc < KC; ++kc) qf[kc] = *(const bf16x8*)(qrow + kc * 32);

  f32x4 of[NC];
#pragma unroll
  for (int i = 0; i < NC; ++i) of[i] = (f32x4){0.f, 0.f, 0.f, 0.f};
  float lsum = 0.f;

  const __bf16* Kb = Kt + (size_t)b * NSP * CD;
  const __bf16* Vbb = Vb + (size_t)b * CD * NSP;

  for (int m0 = ks * KEYS; m0 < (ks + 1) * KEYS; m0 += 32) {
    __syncthreads();
    for (int i = tid; i < 32 * CD / 8; i += 256) {
      int row = i / (CD / 8);
      int cc8 = (i % (CD / 8)) * 8;
      *(bf16x8*)&kl[row][cc8] = *(const bf16x8*)(Kb + (size_t)(m0 + row) * CD + cc8);
    }
    for (int i = tid; i < CD * 4; i += 256) {
      int ch = i / 4;
      int k8 = (i % 4) * 8;
      *(bf16x8*)&vl[ch][k8] = *(const bf16x8*)(Vbb + (size_t)ch * NSP + m0 + k8);
    }
    __syncthreads();
    f32x4 s[2];
#pragma unroll
    for (int t = 0; t < 2; ++t) {
      f32x4 acc = (f32x4){0.f, 0.f, 0.f, 0.f};
#pragma unroll
      for (int kc = 0; kc < KC; ++kc) {
        bf16x8 kf = *(const bf16x8*)&kl[t * 16 + m15][kc * 32 + quad * 8];
        acc = __builtin_amdgcn_mfma_f32_16x16x32_bf16(kf, qf[kc], acc, 0, 0, 0);
      }
      s[t] = acc;
    }
    bf16x8 pf;
#pragma unroll
    for (int t = 0; t < 2; ++t) {
#pragma unroll
      for (int r = 0; r < 4; ++r) {
        float ev = __expf(s[t][r]);
        lsum += ev;
        pf[t * 4 + r] = (__bf16)ev;
      }
    }
#pragma unroll
    for (int ct = 0; ct < NC; ++ct) {
      bf16x4 va = *(const bf16x4*)&vl[ct * 16 + m15][4 * quad];
      bf16x4 vb_ = *(const bf16x4*)&vl[ct * 16 + m15][16 + 4 * quad];
      bf16x8 vf;
#pragma unroll
      for (int j = 0; j < 4; ++j) { vf[j] = va[j]; vf[4 + j] = vb_[j]; }
      of[ct] = __builtin_amdgcn_mfma_f32_16x16x32_bf16(pf, vf, of[ct], 0, 0, 0);
    }
  }

  lsum += __shfl_xor(lsum, 16);
  lsum += __shfl_xor(lsum, 32);
  float* lpb = lp + (size_t)(ks * BB + b) * NSP + n0;
  if (quad == 0) lpb[m15] = lsum;
  __bf16* Ob = Op + (size_t)(ks * BB + b) * CD * NSP;
#pragma unroll
  for (int ct = 0; ct < NC; ++ct) {
    bf16x4 pk;
#pragma unroll
    for (int reg = 0; reg < 4; ++reg) pk[reg] = (__bf16)of[ct][reg];
    *(bf16x4*)(Ob + (size_t)(ct * 16 + m15) * NSP + n0 + quad * 4) = pk;
  }
}

// ---------------- fused combine32 + ps + QKV: comb never materialized ----------------
__global__ __launch_bounds__(256) void c32psqkv_kernel(
    const __bf16* __restrict__ Op, const float* __restrict__ lp,
    const __bf16* __restrict__ wps, const float* __restrict__ ps_b,
    const float* __restrict__ rec, const __bf16* __restrict__ wpqk,
    const float* __restrict__ pq_b, const float* __restrict__ k_b,
    const float* __restrict__ v_b, __bf16* __restrict__ Qt,
    __bf16* __restrict__ K2t, __bf16* __restrict__ V2b, float qscale) {
  __shared__ float lds[32][33];      // att1 [ch][n-local]
  __shared__ __bf16 comb[32][136];   // comb [n-local][ch], 272B rows -> 4-bank rotation
  int b = blockIdx.y;
  int n0 = blockIdx.x * 32;
  int tid = threadIdx.x;
  int nn = tid & 31, cs = tid >> 5;
  float ltot = 0.f;
#pragma unroll
  for (int ks = 0; ks < KS; ++ks) ltot += lp[(size_t)(ks * BB + b) * NSP + n0 + nn];
  float linv = 1.0f / ltot;
#pragma unroll
  for (int j = 0; j < 4; ++j) {
    int cc = cs * 4 + j;
    float s = 0.f;
#pragma unroll
    for (int ks = 0; ks < KS; ++ks)
      s += (float)Op[((size_t)(ks * BB + b) * 32 + cc) * NSP + n0 + nn];
    lds[cc][nn] = s * linv;
  }
  __syncthreads();
  // Phase B: ps (O=128, K=32) + rec -> comb (bf16, identical rounding to old comb_t)
  int wv = tid >> 6, lane = tid & 63;
  int m15 = lane & 15, quad = lane >> 4;
  int o0 = wv * 32;
  bf16x8 a0 = *(const bf16x8*)(wps + (size_t)(o0 + m15) * 32 + quad * 8);
  bf16x8 a1 = *(const bf16x8*)(wps + (size_t)(o0 + 16 + m15) * 32 + quad * 8);
#pragma unroll
  for (int t2 = 0; t2 < 2; ++t2) {
    int nl = t2 * 16 + m15;
    int n = n0 + nl;
    bf16x8 bfr;
#pragma unroll
    for (int j = 0; j < 8; ++j) bfr[j] = (__bf16)lds[quad * 8 + j][nl];
    f32x4 of0 = (f32x4){0.f, 0.f, 0.f, 0.f};
    f32x4 of1 = (f32x4){0.f, 0.f, 0.f, 0.f};
    of0 = __builtin_amdgcn_mfma_f32_16x16x32_bf16(a0, bfr, of0, 0, 0, 0);
    of1 = __builtin_amdgcn_mfma_f32_16x16x32_bf16(a1, bfr, of1, 0, 0, 0);
#pragma unroll
    for (int t = 0; t < 2; ++t) {
      f32x4 acc = t ? of1 : of0;
      bf16x4 pk;
#pragma unroll
      for (int reg = 0; reg < 4; ++reg) {
        int ol = o0 + t * 16 + quad * 4 + reg;
        float v = acc[reg] + ps_b[ol] + rec[((size_t)b * 128 + ol) * NSP + n];
        pk[reg] = (__bf16)v;
      }
      *(bf16x4*)&comb[nl][o0 + t * 16 + quad * 4] = pk;
    }
  }
  __syncthreads();
  // Phase C: QKV (O=384, K=128 from LDS comb). 4 waves x 3 o-tiles.
#pragma unroll
  for (int j = 0; j < 3; ++j) {
    int og = (wv * 3 + j) * 32;
    int seg = og >> 7;          // 0:Q 1:K 2:V
    int ol0 = og & 127;
    const __bf16* a0p = wpqk + (size_t)(og + m15) * 128 + quad * 8;
    const __bf16* a1p = wpqk + (size_t)(og + 16 + m15) * 128 + quad * 8;
#pragma unroll
    for (int t2 = 0; t2 < 2; ++t2) {
      int nl = t2 * 16 + m15;
      int n = n0 + nl;
      f32x4 of0 = (f32x4){0.f, 0.f, 0.f, 0.f};
      f32x4 of1 = (f32x4){0.f, 0.f, 0.f, 0.f};
#pragma unroll
      for (int kc = 0; kc < 128; kc += 32) {
        bf16x8 bfr = *(const bf16x8*)&comb[nl][kc + quad * 8];
        of0 = __builtin_amdgcn_mfma_f32_16x16x32_bf16(*(const bf16x8*)(a0p + kc), bfr, of0, 0, 0, 0);
        of1 = __builtin_amdgcn_mfma_f32_16x16x32_bf16(*(const bf16x8*)(a1p + kc), bfr, of1, 0, 0, 0);
      }
#pragma unroll
      for (int t = 0; t < 2; ++t) {
        f32x4 acc = t ? of1 : of0;
        if (seg == 0) {
          bf16x4 pk;
#pragma unroll
          for (int reg = 0; reg < 4; ++reg)
            pk[reg] = (__bf16)((acc[reg] + pq_b[ol0 + t * 16 + quad * 4 + reg]) * qscale);
          *(bf16x4*)(Qt + ((size_t)b * NSP + n) * 128 + ol0 + t * 16 + quad * 4) = pk;
        } else if (seg == 1) {
          bf16x4 pk;
#pragma unroll
          for (int reg = 0; reg < 4; ++reg)
            pk[reg] = (__bf16)(acc[reg] + k_b[ol0 + t * 16 + quad * 4 + reg]);
          *(bf16x4*)(K2t + ((size_t)b * NSP + n) * 128 + ol0 + t * 16 + quad * 4) = pk;
        } else {
#pragma unroll
          for (int reg = 0; reg < 4; ++reg) {
            int ol = ol0 + t * 16 + quad * 4 + reg;
            V2b[((size_t)b * 128 + ol) * NSP + n] = (__bf16)(acc[reg] + v_b[ol]);
          }
        }
      }
    }
  }
}

// ---------------- fused combine128 + FFN: x1 kept in LDS, out written directly ----------------
__global__ __launch_bounds__(256) void c128ffn_kernel(
    const __bf16* __restrict__ Op, const float* __restrict__ lp,
    const float* __restrict__ x, const __bf16* __restrict__ wfc1,
    const float* __restrict__ fc1_b, const __bf16* __restrict__ wfc2,
    const float* __restrict__ fc2_b, float* __restrict__ outp) {
  __shared__ float x1f[16][132];   // 528B rows -> 4-bank rotation
  __shared__ __bf16 x1l[16][136];  // 272B rows
  __shared__ __bf16 hl[16][520];   // 1040B rows
  int tid = threadIdx.x;
  int b = blockIdx.y;
  int n0 = blockIdx.x * 16;
  // phase A: combine 4 key-split partials + x residual for 16 rows x 128 ch
  {
    int r = tid & 15, g = tid >> 4;  // g in [0,16)
    float ltot = 0.f;
#pragma unroll
    for (int ks = 0; ks < KS; ++ks) ltot += lp[(size_t)(ks * BB + b) * NSP + n0 + r];
    float linv = 1.0f / ltot;
#pragma unroll
    for (int j = 0; j < 8; ++j) {
      int ch = g * 8 + j;
      float s = 0.f;
#pragma unroll
      for (int ks = 0; ks < KS; ++ks)
        s += (float)Op[((size_t)(ks * BB + b) * CC + ch) * NSP + n0 + r];
      float v = s * linv + x[((size_t)b * CC + ch) * NSP + n0 + r];
      x1f[r][ch] = v;
      x1l[r][ch] = (__bf16)v;
    }
  }
  __syncthreads();
  // phase B: fc1 (O=512, K=128 from x1l), relu^2 -> hl
  int wv = tid >> 6, lane = tid & 63;
  int m15 = lane & 15, quad = lane >> 4;
  bf16x8 bf[4];
#pragma unroll
  for (int kc = 0; kc < 4; ++kc) bf[kc] = *(const bf16x8*)&x1l[m15][kc * 32 + quad * 8];
#pragma unroll
  for (int j = 0; j < 4; ++j) {
    int o0 = (wv * 4 + j) * 32;
    const __bf16* a0p = wfc1 + (size_t)(o0 + m15) * 128 + quad * 8;
    const __bf16* a1p = wfc1 + (size_t)(o0 + 16 + m15) * 128 + quad * 8;
    f32x4 of0 = (f32x4){0.f, 0.f, 0.f, 0.f};
    f32x4 of1 = (f32x4){0.f, 0.f, 0.f, 0.f};
#pragma unroll
    for (int kc = 0; kc < 4; ++kc) {
      of0 = __builtin_amdgcn_mfma_f32_16x16x32_bf16(*(const bf16x8*)(a0p + kc * 32), bf[kc], of0, 0, 0, 0);
      of1 = __builtin_amdgcn_mfma_f32_16x16x32_bf16(*(const bf16x8*)(a1p + kc * 32), bf[kc], of1, 0, 0, 0);
    }
#pragma unroll
    for (int t = 0; t < 2; ++t) {
      f32x4 acc = t ? of1 : of0;
      bf16x4 pk;
#pragma unroll
      for (int reg = 0; reg < 4; ++reg) {
        float v = fmaxf(acc[reg] + fc1_b[o0 + t * 16 + quad * 4 + reg], 0.0f);
        pk[reg] = (__bf16)(v * v);
      }
      *(bf16x4*)&hl[m15][o0 + t * 16 + quad * 4] = pk;
    }
  }
  __syncthreads();
  // phase C: fc2 (O=128, K=512 from hl) + x1f residual -> outp f32 planar
  int o0 = wv * 32;
  const __bf16* a0p = wfc2 + (size_t)(o0 + m15) * 512 + quad * 8;
  const __bf16* a1p = wfc2 + (size_t)(o0 + 16 + m15) * 512 + quad * 8;
  f32x4 of0 = (f32x4){0.f, 0.f, 0.f, 0.f};
  f32x4 of1 = (f32x4){0.f, 0.f, 0.f, 0.f};
#pragma unroll
  for (int kc = 0; kc < 512; kc += 32) {
    bf16x8 bfr = *(const bf16x8*)&hl[m15][kc + quad * 8];
    of0 = __builtin_amdgcn_mfma_f32_16x16x32_bf16(*(const bf16x8*)(a0p + kc), bfr, of0, 0, 0, 0);
    of1 = __builtin_amdgcn_mfma_f32_16x16x32_bf16(*(const bf16x8*)(a1p + kc), bfr, of1, 0, 0, 0);
  }
  int n = n0 + m15;
#pragma unroll
  for (int t = 0; t < 2; ++t) {
    f32x4 acc = t ? of1 : of0;
#pragma unroll
    for (int reg = 0; reg < 4; ++reg) {
      int ol = o0 + t * 16 + quad * 4 + reg;
      outp[((size_t)b * 128 + ol) * NSP + n] = acc[reg] + fc2_b[ol] + x1f[m15][ol];
    }
  }
}

// ---------------- host ----------------
extern "C" void kernel_launch(void* const* d_in, const int* in_sizes, int n_in,
                              void* d_out, int out_size, void* d_ws, size_t ws_size,
                              hipStream_t stream) {
  const float* x = (const float*)d_in[0];
  const float* r_w = (const float*)d_in[1];
  const float* r_b = (const float*)d_in[2];
  const float* k_w = (const float*)d_in[3];
  const float* k_b = (const float*)d_in[4];
  const float* v_w = (const float*)d_in[5];
  const float* v_b = (const float*)d_in[6];
  // d_in[7..10]: wc1/wc2 — dead code (multiplied by zeros in reference)
  const float* u = (const float*)d_in[11];
  const float* sn1_w = (const float*)d_in[12];
  const float* sn1_b = (const float*)d_in[13];
  const float* sn2_w = (const float*)d_in[14];
  const float* sn2_b = (const float*)d_in[15];
  const float* lb_w = (const float*)d_in[16];
  const float* lb_b = (const float*)d_in[17];
  const float* ld_w = (const float*)d_in[18];
  const float* ld_b = (const float*)d_in[19];
  const float* ps_w = (const float*)d_in[20];
  const float* ps_b = (const float*)d_in[21];
  const float* pq_w = (const float*)d_in[22];
  const float* pq_b = (const float*)d_in[23];
  const float* fc1_w = (const float*)d_in[24];
  const float* fc1_b = (const float*)d_in[25];
  const float* fc2_w = (const float*)d_in[26];
  const float* fc2_b = (const float*)d_in[27];
  const float* db_g[4] = {(const float*)d_in[28], (const float*)d_in[32],
                          (const float*)d_in[36], (const float*)d_in[40]};
  const float* db_b[4] = {(const float*)d_in[29], (const float*)d_in[33],
                          (const float*)d_in[37], (const float*)d_in[41]};
  const float* db_w[4] = {(const float*)d_in[30], (const float*)d_in[34],
                          (const float*)d_in[38], (const float*)d_in[42]};
  const float* db_cb[4] = {(const float*)d_in[31], (const float*)d_in[35],
                           (const float*)d_in[39], (const float*)d_in[43]};

  float* outp = (float*)d_out;           // out  (B,C,H,W)
  float* knum = outp + BCN;              // new_num = k*v
  float* kden = outp + 2 * (size_t)BCN;  // new_den = k

  float* ws = (float*)d_ws;
  // region map (f32 slots)
  const size_t F_FEATS = 0;         // cpart0/1/2 + bnrelu -> Op partials (KS=4 CD=128)
  const size_t F_BNR = 131072;      // bnrelu bf16 (B,N,256) = 1179648 f32 slots (dead after convs)
  const size_t F_REC = 4718592;     // rec f32 (1179648)
  const size_t F_V = 5898240;       // V2b bf16 (589824)
  const size_t F_R = 7077888;       // dense_t bf16 (589824)
  const size_t F_XR = 8257536;      // xrope_t bf16 -> Qt (589824)
  const size_t F_XT = 8847360;      // x_t bf16 -> K2t (589824)
  const size_t F_DFB = 9437184;     // Dfb bf16 (147456)
  const size_t F_CT = 9732096;      // Bft (upper half)
  const size_t F_LP = 10321920;     // lp f32 (KS*B*NSP = 36864)
  const size_t F_WB = 10434048;     // conv1x1 weights bf16 (282624 bf16 = 141312 slots)
  const size_t F_WB3 = 10575360;    // conv3x3 packed weights bf16 (202752 bf16 = 101376 slots)
  const size_t F_STATS = 10676736;  // sums[256] sums2[256]
  const size_t F_TAUP = 10714112;   // tau partials (1024 x 144 = 147456)
  float* sums = ws + F_STATS;
  float* sums2 = ws + F_STATS + 256;
  float* cpart0 = ws + F_FEATS;        // conv stat partials, per layer (64 x 576 each)
  float* cpart1 = cpart0 + 36864;
  float* cpart2 = cpart1 + 36864;
  __bf16* bnrelu = (__bf16*)(ws + F_BNR);
  float* taupart = ws + F_TAUP;
  float* lp = ws + F_LP;
  __bf16* wbase = (__bf16*)(ws + F_WB);
  __bf16* wb3 = (__bf16*)(ws + F_WB3);
  const int W_KV = 0;        // k(16384) | v(16384)
  const int W_R = 32768;     // 16384
  const int W_SN1 = 49152;   // 16384
  const int W_SN2 = 65536;   // 16384
  const int W_LBLD = 81920;  // lb(8192) | ld(8192)
  const int W_PS = 98304;    // 4096
  const int W_PQK = 102400;  // pq(16384) | k(16384) | v(16384)
  const int W_FC1 = 151552;  // 65536
  const int W_FC2 = 217088;  // 65536
  const int W3_OFF[4] = {0, 36864, 82944, 138240};

  dim3 blk(256);
  __bf16* xrope_t = (__bf16*)(ws + F_XR);
  __bf16* x_t = (__bf16*)(ws + F_XT);

  // --- prep: weight cvt + conv pack + x stats + x dual-transpose, ONE launch ---
  Prep pp;
  pp.wsrc[0] = k_w;    pp.wlen[0] = 16384; pp.woff[0] = W_KV;
  pp.wsrc[1] = v_w;    pp.wlen[1] = 16384; pp.woff[1] = W_KV + 16384;
  pp.wsrc[2] = r_w;    pp.wlen[2] = 16384; pp.woff[2] = W_R;
  pp.wsrc[3] = sn1_w;  pp.wlen[3] = 16384; pp.woff[3] = W_SN1;
  pp.wsrc[4] = sn2_w;  pp.wlen[4] = 16384; pp.woff[4] = W_SN2;
  pp.wsrc[5] = lb_w;   pp.wlen[5] = 8192;  pp.woff[5] = W_LBLD;
  pp.wsrc[6] = ld_w;   pp.wlen[6] = 8192;  pp.woff[6] = W_LBLD + 8192;
  pp.wsrc[7] = ps_w;   pp.wlen[7] = 4096;  pp.woff[7] = W_PS;
  pp.wsrc[8] = pq_w;   pp.wlen[8] = 16384; pp.woff[8] = W_PQK;
  pp.wsrc[9] = k_w;    pp.wlen[9] = 16384; pp.woff[9] = W_PQK + 16384;
  pp.wsrc[10] = v_w;   pp.wlen[10] = 16384; pp.woff[10] = W_PQK + 32768;
  pp.wsrc[11] = fc1_w; pp.wlen[11] = 65536; pp.woff[11] = W_FC1;
  pp.wsrc[12] = fc2_w; pp.wlen[12] = 65536; pp.woff[12] = W_FC2;
  for (int i = 0; i < 4; ++i) {
    pp.psrc[i] = db_w[i];
    pp.pcin[i] = 128 + 32 * i;
    pp.poff[i] = W3_OFF[i];
  }
  pp.x = x;
  pp.sums = sums;
  pp.sums2 = sums2;
  pp.x_t = x_t;
  pp.xrope_t = xrope_t;
  prep_kernel<<<dim3(256, 23), blk, 0, stream>>>(pp, wbase, wb3);

  // --- recurrent path: ONE fused k|v|r GEMM + rwkv epilogue ---
  kvr_kernel<<<dim3(144, 4), blk, 0, stream>>>(
      xrope_t, x_t, wbase + W_KV, wbase + W_KV + 16384, wbase + W_R,
      k_b, v_b, r_b, u, kden, knum, ws + F_REC);

  // --- dense block: conv with cached BN activations (bnrelu) ---
  __bf16* dense_t = (__bf16*)(ws + F_R);
  convbn_kernel<128><<<dim3(144, 4), blk, 0, stream>>>(
      x_t, dense_t, bnrelu, wb3 + W3_OFF[0], db_cb[0], sums, sums2, nullptr,
      db_g[0], db_b[0], dense_t, cpart0, 128, 0);
  convbn_kernel<160><<<dim3(144, 4), blk, 0, stream>>>(
      x_t, dense_t, bnrelu, wb3 + W3_OFF[1], db_cb[1], sums, sums2, cpart0,
      db_g[1], db_b[1], dense_t, cpart1, 160, 128);
  convbn_kernel<192><<<dim3(144, 4), blk, 0, stream>>>(
      x_t, dense_t, bnrelu, wb3 + W3_OFF[2], db_cb[2], sums, sums2, cpart1,
      db_g[2], db_b[2], dense_t, cpart2, 192, 160);
  convbn_kernel<224><<<dim3(144, 4), blk, 0, stream>>>(
      x_t, dense_t, bnrelu, wb3 + W3_OFF[3], db_cb[3], sums, sums2, cpart2,
      db_g[3], db_b[3], dense_t, nullptr, 224, 192);

  // --- spike path: fused sn1+sn2 (tau partials), sf inline in lb/ld GEMM ---
  sn12_kernel<<<dim3(144, 4), blk, 0, stream>>>(
      x_t, dense_t, wbase + W_SN1, sn1_b, wbase + W_SN2, sn2_b, taupart);
  __bf16* Bft = (__bf16*)(ws + F_CT + 294912);  // upper half of F_CT region
  __bf16* Dfb = (__bf16*)(ws + F_DFB);
  lbld_sf_kernel<<<dim3(144, 4), dim3(128), 0, stream>>>(
      x_t, dense_t, taupart, wbase + W_LBLD, lb_b, ld_b, Bft, Dfb);
  __bf16* Opart = (__bf16*)(ws + F_FEATS);  // cpart+bnrelu dead from here
  attn_part_kernel<32><<<dim3(36, 4, KS), blk, 0, stream>>>(Bft, Bft, Dfb, Opart, lp);

  // --- fused combine32+ps+QKV (comb never hits memory) ---
  __bf16* Qt = (__bf16*)(ws + F_XR);   // xrope_t dead after kvr
  __bf16* K2t = (__bf16*)(ws + F_XT);  // x_t dead after lbld_sf
  __bf16* V2b = (__bf16*)(ws + F_V);
  c32psqkv_kernel<<<dim3(72, 4), blk, 0, stream>>>(
      Opart, lp, wbase + W_PS, ps_b, ws + F_REC, wbase + W_PQK,
      pq_b, k_b, v_b, Qt, K2t, V2b, 0.08838834764831845f);

  // --- final attention + fused combine128+FFN (x1/x1_t/h never hit memory) ---
  attn_part_kernel<128><<<dim3(36, 4, KS), blk, 0, stream>>>(Qt, K2t, V2b, Opart, lp);
  c128ffn_kernel<<<dim3(144, 4), blk, 0, stream>>>(
      Opart, lp, x, wbase + W_FC1, fc1_b, wbase + W_FC2, fc2_b, outp);
}

// Round 14
// 370.362 us; speedup vs baseline: 1.0403x; 1.0403x over previous
//
#include <hip/hip_runtime.h>
#include <math.h>

#define BB 4
#define CC 128
#define HH 48
#define WW 48
#define NSP (HH*WW)          // 2304
#define DCC 256
#define BCN (BB*CC*NSP)      // 1179648
#define KS 4                 // attention key-splits

typedef float f32x4 __attribute__((ext_vector_type(4)));
typedef __bf16 bf16x8 __attribute__((ext_vector_type(8)));
typedef __bf16 bf16x4 __attribute__((ext_vector_type(4)));

__device__ __forceinline__ float sigmf(float v) { return 1.0f / (1.0f + __expf(-v)); }

// ---------------- merged prep: weight cvt (13) + conv3x3 pack (4) + x-stats + x dual-transpose ----------------
struct Prep {
  const float* wsrc[13];
  int wlen[13];
  int woff[13];
  const float* psrc[4];
  int pcin[4];
  int poff[4];
  const float* x;
  float* sums;
  float* sums2;
  __bf16* x_t;
  __bf16* xrope_t;
};
__global__ __launch_bounds__(256) void prep_kernel(Prep a, __bf16* __restrict__ wdst,
                                                   __bf16* __restrict__ pdst) {
  __shared__ float lds[32][33];
  __shared__ float rs[4], rs2[4];
  int g = blockIdx.y;
  int idx = blockIdx.x * 256 + threadIdx.x;
  if (g < 13) {
    if (idx < a.wlen[g]) wdst[a.woff[g] + idx] = (__bf16)a.wsrc[g][idx];
  } else if (g < 17) {
    int L = g - 13;
    int cin = a.pcin[L];
    if (idx < 9 * 32 * cin) {
      int c = idx % cin;
      int o = (idx / cin) % 32;
      int tap = idx / (cin * 32);
      pdst[a.poff[L] + idx] = (__bf16)a.psrc[L][((size_t)o * cin + c) * 9 + tap];
    }
  } else if (g == 17) {
    // x-channel BN stats: one block per channel (plain stores, no atomics)
    int c = blockIdx.x;
    if (c >= 128) return;
    float s = 0.f, s2 = 0.f;
    for (int i = threadIdx.x; i < BB * NSP; i += 256) {
      int b = i / NSP, n = i % NSP;
      float v = a.x[((size_t)b * 128 + c) * NSP + n];
      s += v;
      s2 += v * v;
    }
#pragma unroll
    for (int off = 32; off > 0; off >>= 1) {
      s += __shfl_down(s, off);
      s2 += __shfl_down(s2, off);
    }
    int wid = threadIdx.x >> 6;
    if ((threadIdx.x & 63) == 0) { rs[wid] = s; rs2[wid] = s2; }
    __syncthreads();
    if (threadIdx.x == 0) {
      a.sums[c] = rs[0] + rs[1] + rs[2] + rs[3];
      a.sums2[c] = rs2[0] + rs2[1] + rs2[2] + rs2[3];
    }
  } else {
    // dual transpose x -> x_t (plain) + xrope_t (RoPE), LDS-tiled
    int T = (g - 18) * 256 + blockIdx.x;
    if (T >= 1152) return;
    int b = T / 288;
    int r = T % 288;
    int c0 = (r / 72) * 32;
    int n0 = (r % 72) * 32;
    int tid = threadIdx.x;
    int nn = tid & 31, cs = tid >> 5;
#pragma unroll
    for (int j = 0; j < 4; ++j) {
      int cc = c0 + cs * 4 + j;
      lds[cs * 4 + j][nn] = a.x[((size_t)b * 128 + cc) * NSP + n0 + nn];
    }
    __syncthreads();
    int c = tid & 31, ns = tid >> 5;
#pragma unroll
    for (int j = 0; j < 4; ++j) {
      int n2 = ns * 4 + j;
      float pv = lds[c][n2];
      a.x_t[((size_t)b * NSP + n0 + n2) * 128 + c0 + c] = (__bf16)pv;
      int gc = c0 + c;
      int i = gc >> 1;
      float re = lds[c & ~1][n2];
      float im = lds[c | 1][n2];
      int n = n0 + n2;
      int h = n / WW, w = n % WW;
      float theta = __expf(-9.2103403719761836f * ((float)i) / 64.0f);
      float pos = (float)(h + w) * theta;
      float cs_ = cosf(pos), sn_ = sinf(pos);
      float vr_ = (gc & 1) ? (re * sn_ + im * cs_) : (re * cs_ - im * sn_);
      a.xrope_t[((size_t)b * NSP + n0 + n2) * 128 + c0 + c] = (__bf16)vr_;
    }
  }
}

// ---------------- combined conv-layer-0 + kvr (independent work, one launch) ----------------
// blockIdx.z == 0: conv3x3 layer 0 (Cin=128, inline BN from sums).  z == 1: k|v|r GEMM + rwkv.
__global__ __launch_bounds__(256) void conv128kvr_kernel(
    const __bf16* __restrict__ x_t, const __bf16* __restrict__ xrope_t,
    const __bf16* __restrict__ wb, const float* __restrict__ cb,
    const float* __restrict__ sums, const float* __restrict__ sums2,
    const float* __restrict__ g, const float* __restrict__ bbp,
    __bf16* __restrict__ dense_out, float* __restrict__ cpart_out,
    const __bf16* __restrict__ wk, const __bf16* __restrict__ wvp,
    const __bf16* __restrict__ wr,
    const float* __restrict__ k_b, const float* __restrict__ v_b,
    const float* __restrict__ r_b, const float* __restrict__ u,
    float* __restrict__ kden, float* __restrict__ knum, float* __restrict__ rec) {
  int tid = threadIdx.x;
  int wv = tid >> 6, lane = tid & 63;
  int m15 = lane & 15, quad = lane >> 4;
  int b = blockIdx.y;
  int n0 = blockIdx.x * 16;
  int n = n0 + m15;

  if (blockIdx.z == 1) {
    // ---- kvr path ----
    int o0 = wv * 32;
    const __bf16* brr = xrope_t + ((size_t)b * NSP + n) * 128 + quad * 8;
    const __bf16* brx = x_t + ((size_t)b * NSP + n) * 128 + quad * 8;
    const __bf16* ak0 = wk + (size_t)(o0 + m15) * 128 + quad * 8;
    const __bf16* ak1 = wk + (size_t)(o0 + 16 + m15) * 128 + quad * 8;
    const __bf16* av0 = wvp + (size_t)(o0 + m15) * 128 + quad * 8;
    const __bf16* av1 = wvp + (size_t)(o0 + 16 + m15) * 128 + quad * 8;
    const __bf16* ar0 = wr + (size_t)(o0 + m15) * 128 + quad * 8;
    const __bf16* ar1 = wr + (size_t)(o0 + 16 + m15) * 128 + quad * 8;
    f32x4 fk[2], fv[2], fr[2];
#pragma unroll
    for (int t = 0; t < 2; ++t) {
      fk[t] = (f32x4){0.f, 0.f, 0.f, 0.f};
      fv[t] = (f32x4){0.f, 0.f, 0.f, 0.f};
      fr[t] = (f32x4){0.f, 0.f, 0.f, 0.f};
    }
#pragma unroll
    for (int kc = 0; kc < 128; kc += 32) {
      bf16x8 br_ = *(const bf16x8*)(brr + kc);
      bf16x8 bx_ = *(const bf16x8*)(brx + kc);
      fk[0] = __builtin_amdgcn_mfma_f32_16x16x32_bf16(*(const bf16x8*)(ak0 + kc), br_, fk[0], 0, 0, 0);
      fk[1] = __builtin_amdgcn_mfma_f32_16x16x32_bf16(*(const bf16x8*)(ak1 + kc), br_, fk[1], 0, 0, 0);
      fv[0] = __builtin_amdgcn_mfma_f32_16x16x32_bf16(*(const bf16x8*)(av0 + kc), br_, fv[0], 0, 0, 0);
      fv[1] = __builtin_amdgcn_mfma_f32_16x16x32_bf16(*(const bf16x8*)(av1 + kc), br_, fv[1], 0, 0, 0);
      fr[0] = __builtin_amdgcn_mfma_f32_16x16x32_bf16(*(const bf16x8*)(ar0 + kc), bx_, fr[0], 0, 0, 0);
      fr[1] = __builtin_amdgcn_mfma_f32_16x16x32_bf16(*(const bf16x8*)(ar1 + kc), bx_, fr[1], 0, 0, 0);
    }
#pragma unroll
    for (int t = 0; t < 2; ++t) {
#pragma unroll
      for (int reg = 0; reg < 4; ++reg) {
        int ol = o0 + t * 16 + quad * 4 + reg;
        float kk = fk[t][reg] + k_b[ol];
        float vv = fv[t][reg] + v_b[ol];
        float rr = sigmf(fr[t][reg] + r_b[ol]);
        float eu = __expf(u[ol]);
        size_t idx = ((size_t)b * 128 + ol) * NSP + n;
        float nv = kk * vv, tt = eu * kk;
        kden[idx] = kk;
        knum[idx] = nv;
        rec[idx] = rr * ((nv + tt * vv) / (kk + tt));
      }
    }
    return;
  }

  // ---- conv layer 0 path (Cin=128) ----
  constexpr int Cin = 128;
  constexpr int NIT = 9 * (Cin / 32);
  __shared__ float red[4][64][8];
  __shared__ float scsh[2][Cin];
  const float inv = 1.0f / (float)(BB * NSP);
  for (int ch = tid; ch < Cin; ch += 256) {
    float m = sums[ch] * inv;
    float var = sums2[ch] * inv - m * m;
    float sc_ = rsqrtf(var + 1e-5f) * g[ch];
    scsh[0][ch] = sc_;
    scsh[1][ch] = bbp[ch] - m * sc_;
  }
  __syncthreads();

  int h = n / WW, w = n % WW;
  f32x4 of0 = (f32x4){0.f, 0.f, 0.f, 0.f};
  f32x4 of1 = (f32x4){0.f, 0.f, 0.f, 0.f};
  const __bf16* bx_ = x_t + (size_t)b * NSP * 128;
  const bf16x8 zf = {};
  int begin = (wv * NIT) / 4, end = ((wv + 1) * NIT) / 4;
  int cur = -1;
  float bsc[8], bsh[8];
  const __bf16* base = nullptr;
  for (int ci = begin; ci < end; ++ci) {
    int chunk = ci / 9;
    int tap = ci - chunk * 9;
    int kc = chunk * 32;
    if (chunk != cur) {
      cur = chunk;
      int cc = kc + quad * 8;
#pragma unroll
      for (int j = 0; j < 8; ++j) {
        bsc[j] = scsh[0][cc + j];
        bsh[j] = scsh[1][cc + j];
      }
      base = bx_ + cc;
    }
    int dh = tap / 3 - 1, dw = tap % 3 - 1;
    bool valid = ((unsigned)(h + dh) < HH) && ((unsigned)(w + dw) < WW);
    int pa = valid ? (n + dh * WW + dw) : 0;
    bf16x8 raw = *(const bf16x8*)(base + (size_t)pa * 128);
    bf16x8 bfr;
#pragma unroll
    for (int j = 0; j < 8; ++j) {
      float v = fmaxf((float)raw[j] * bsc[j] + bsh[j], 0.0f);
      bfr[j] = (__bf16)v;
    }
    if (!valid) bfr = zf;
    const __bf16* wt = wb + (size_t)tap * 32 * Cin + kc + quad * 8;
    bf16x8 a0 = *(const bf16x8*)(wt + (size_t)m15 * Cin);
    bf16x8 a1 = *(const bf16x8*)(wt + (size_t)(16 + m15) * Cin);
    of0 = __builtin_amdgcn_mfma_f32_16x16x32_bf16(a0, bfr, of0, 0, 0, 0);
    of1 = __builtin_amdgcn_mfma_f32_16x16x32_bf16(a1, bfr, of1, 0, 0, 0);
  }
  float* myred = red[wv][lane];
#pragma unroll
  for (int reg = 0; reg < 4; ++reg) {
    myred[reg] = of0[reg];
    myred[4 + reg] = of1[reg];
  }
  __syncthreads();
  if (wv == 0) {
    __bf16* dt = dense_out + ((size_t)b * NSP + n) * 128;  // cout0=128 -> dloc 0
    bf16x4 pk0, pk1;
    float sv[4][4];
#pragma unroll
    for (int reg = 0; reg < 4; ++reg) {
      int o = quad * 4 + reg;
      float v0 = red[0][lane][reg] + red[1][lane][reg] + red[2][lane][reg] +
                 red[3][lane][reg] + cb[o];
      float v1 = red[0][lane][4 + reg] + red[1][lane][4 + reg] + red[2][lane][4 + reg] +
                 red[3][lane][4 + reg] + cb[16 + o];
      pk0[reg] = (__bf16)v0;
      pk1[reg] = (__bf16)v1;
      sv[reg][0] = v0;
      sv[reg][1] = v0 * v0;
      sv[reg][2] = v1;
      sv[reg][3] = v1 * v1;
    }
    *(bf16x4*)(dt + quad * 4) = pk0;
    *(bf16x4*)(dt + 16 + quad * 4) = pk1;
#pragma unroll
    for (int reg = 0; reg < 4; ++reg) {
      float a0 = sv[reg][0], q0 = sv[reg][1], a1 = sv[reg][2], q1 = sv[reg][3];
#pragma unroll
      for (int mk = 1; mk < 16; mk <<= 1) {
        a0 += __shfl_xor(a0, mk);
        q0 += __shfl_xor(q0, mk);
        a1 += __shfl_xor(a1, mk);
        q1 += __shfl_xor(q1, mk);
      }
      if (m15 == 0) {
        int o = quad * 4 + reg;
        int pidx = blockIdx.y * 144 + blockIdx.x;
        cpart_out[(size_t)o * 576 + pidx] = a0;
        cpart_out[(size_t)(32 + o) * 576 + pidx] = q0;
        cpart_out[(size_t)(16 + o) * 576 + pidx] = a1;
        cpart_out[(size_t)(48 + o) * 576 + pidx] = q1;
      }
    }
  }
}

// ---------------- fused sn1+sn2: z1 kept in LDS, tau partials out ----------------
__global__ __launch_bounds__(256) void sn12_kernel(
    const __bf16* __restrict__ x_t, const __bf16* __restrict__ dense_t,
    const __bf16* __restrict__ wsn1, const float* __restrict__ sn1_b,
    const __bf16* __restrict__ wsn2, const float* __restrict__ sn2_b,
    float* __restrict__ taupart) {
  __shared__ __bf16 z1l[16][72];
  int tid = threadIdx.x;
  int wv = tid >> 6, lane = tid & 63;
  int m15 = lane & 15, quad = lane >> 4;
  int b = blockIdx.y;
  int n0 = blockIdx.x * 16;
  int n = n0 + m15;
  if (wv < 2) {
    int o0 = wv * 32;
    const __bf16* bx = x_t + ((size_t)b * NSP + n) * 128 + quad * 8;
    const __bf16* bd = dense_t + ((size_t)b * NSP + n) * 128 + quad * 8;
    const __bf16* a0p = wsn1 + (size_t)(o0 + m15) * 256 + quad * 8;
    const __bf16* a1p = wsn1 + (size_t)(o0 + 16 + m15) * 256 + quad * 8;
    f32x4 of0 = (f32x4){0.f, 0.f, 0.f, 0.f};
    f32x4 of1 = (f32x4){0.f, 0.f, 0.f, 0.f};
#pragma unroll
    for (int kc = 0; kc < 256; kc += 32) {
      bf16x8 bfr = (kc < 128) ? *(const bf16x8*)(bx + kc) : *(const bf16x8*)(bd + (kc - 128));
      bf16x8 a0 = *(const bf16x8*)(a0p + kc);
      bf16x8 a1 = *(const bf16x8*)(a1p + kc);
      of0 = __builtin_amdgcn_mfma_f32_16x16x32_bf16(a0, bfr, of0, 0, 0, 0);
      of1 = __builtin_amdgcn_mfma_f32_16x16x32_bf16(a1, bfr, of1, 0, 0, 0);
    }
#pragma unroll
    for (int t = 0; t < 2; ++t) {
      f32x4 acc = t ? of1 : of0;
#pragma unroll
      for (int reg = 0; reg < 4; ++reg) {
        int ol = o0 + t * 16 + quad * 4 + reg;
        z1l[m15][ol] = (__bf16)fmaxf(acc[reg] + sn1_b[ol], 0.0f);
      }
    }
  }
  __syncthreads();
  bf16x8 bfr0 = *(const bf16x8*)&z1l[m15][quad * 8];
  bf16x8 bfr1 = *(const bf16x8*)&z1l[m15][32 + quad * 8];
#pragma unroll
  for (int ot = 0; ot < 2; ++ot) {
    int o0 = (wv * 2 + ot) * 32;
    const __bf16* a0p = wsn2 + (size_t)(o0 + m15) * 64 + quad * 8;
    const __bf16* a1p = wsn2 + (size_t)(o0 + 16 + m15) * 64 + quad * 8;
    f32x4 of0 = (f32x4){0.f, 0.f, 0.f, 0.f};
    f32x4 of1 = (f32x4){0.f, 0.f, 0.f, 0.f};
    of0 = __builtin_amdgcn_mfma_f32_16x16x32_bf16(*(const bf16x8*)(a0p), bfr0, of0, 0, 0, 0);
    of0 = __builtin_amdgcn_mfma_f32_16x16x32_bf16(*(const bf16x8*)(a0p + 32), bfr1, of0, 0, 0, 0);
    of1 = __builtin_amdgcn_mfma_f32_16x16x32_bf16(*(const bf16x8*)(a1p), bfr0, of1, 0, 0, 0);
    of1 = __builtin_amdgcn_mfma_f32_16x16x32_bf16(*(const bf16x8*)(a1p + 32), bfr1, of1, 0, 0, 0);
#pragma unroll
    for (int t = 0; t < 2; ++t) {
      f32x4 acc = t ? of1 : of0;
#pragma unroll
      for (int reg = 0; reg < 4; ++reg) {
        int ol = o0 + t * 16 + quad * 4 + reg;
        float sv = sigmf(acc[reg] + sn2_b[ol]);
        sv += __shfl_xor(sv, 1);
        sv += __shfl_xor(sv, 2);
        sv += __shfl_xor(sv, 4);
        sv += __shfl_xor(sv, 8);
        if (m15 == 0)
          taupart[((size_t)(b * DCC + ol)) * 144 + blockIdx.x] = sv;
      }
    }
  }
}

// ---------------- lb|ld GEMM with inline spike-fn B (sf never materialized) ----------------
__global__ __launch_bounds__(128) void lbld_sf_kernel(
    const __bf16* __restrict__ x_t, const __bf16* __restrict__ dense_t,
    const float* __restrict__ taupart, const __bf16* __restrict__ wlb,
    const float* __restrict__ lb_b, const float* __restrict__ ld_b,
    __bf16* __restrict__ Bft, __bf16* __restrict__ Dfb) {
  __shared__ float ef[256];
  int tid = threadIdx.x;
  int b = blockIdx.y;
  for (int ch = tid; ch < 256; ch += 128) {
    const f32x4* tp = (const f32x4*)(taupart + ((size_t)(b * DCC + ch)) * 144);
    f32x4 s4 = (f32x4){0.f, 0.f, 0.f, 0.f};
#pragma unroll
    for (int j = 0; j < 36; ++j) s4 += tp[j];
    float tv = (s4.x + s4.y + s4.z + s4.w) * (1.0f / (float)NSP);
    ef[ch] = __expf(-1.0f / (tv + 1e-6f)) - 1.0f;
  }
  __syncthreads();
  int wv = tid >> 6, lane = tid & 63;
  int m15 = lane & 15, quad = lane >> 4;
  int n0 = blockIdx.x * 16;
  int o0 = wv * 32;
  int n = n0 + m15;
  const __bf16* bx = x_t + ((size_t)b * NSP + n) * 128 + quad * 8;
  const __bf16* bd = dense_t + ((size_t)b * NSP + n) * 128 + quad * 8;
  const __bf16* a0p = wlb + (size_t)(o0 + m15) * 256 + quad * 8;
  const __bf16* a1p = wlb + (size_t)(o0 + 16 + m15) * 256 + quad * 8;
  f32x4 of0 = (f32x4){0.f, 0.f, 0.f, 0.f};
  f32x4 of1 = (f32x4){0.f, 0.f, 0.f, 0.f};
#pragma unroll
  for (int kc = 0; kc < 256; kc += 32) {
    bf16x8 raw = (kc < 128) ? *(const bf16x8*)(bx + kc) : *(const bf16x8*)(bd + (kc - 128));
    bf16x8 sfv;
#pragma unroll
    for (int j = 0; j < 8; ++j) {
      float df = (float)raw[j];
      float sp = sigmf((df - 1.0f) * 5.0f);
      sfv[j] = (__bf16)(df * (1.0f + sp * ef[kc + quad * 8 + j]));
    }
    bf16x8 a0 = *(const bf16x8*)(a0p + kc);
    bf16x8 a1 = *(const bf16x8*)(a1p + kc);
    of0 = __builtin_amdgcn_mfma_f32_16x16x32_bf16(a0, sfv, of0, 0, 0, 0);
    of1 = __builtin_amdgcn_mfma_f32_16x16x32_bf16(a1, sfv, of1, 0, 0, 0);
  }
  if (o0 == 0) {
#pragma unroll
    for (int t = 0; t < 2; ++t) {
      f32x4 acc = t ? of1 : of0;
      bf16x4 pk;
#pragma unroll
      for (int reg = 0; reg < 4; ++reg) pk[reg] = (__bf16)(acc[reg] + lb_b[t * 16 + quad * 4 + reg]);
      *(bf16x4*)(Bft + ((size_t)b * NSP + n) * 32 + t * 16 + quad * 4) = pk;
    }
  } else {
#pragma unroll
    for (int t = 0; t < 2; ++t) {
      f32x4 acc = t ? of1 : of0;
#pragma unroll
      for (int reg = 0; reg < 4; ++reg) {
        int ol = t * 16 + quad * 4 + reg;
        Dfb[((size_t)b * 32 + ol) * NSP + n] = (__bf16)(acc[reg] + ld_b[ol]);
      }
    }
  }
}

// ---------------- conv3x3 with inline BN+ReLU on the B-load (round-12 form) ----------------
template <int Cin>
__global__ __launch_bounds__(256) void convbn_kernel(
    const __bf16* __restrict__ x_t, const __bf16* __restrict__ dense_t,
    const __bf16* __restrict__ wb, const float* __restrict__ cb,
    float* __restrict__ sums, float* __restrict__ sums2,
    const float* __restrict__ cpart_in,
    const float* __restrict__ g, const float* __restrict__ bbp,
    __bf16* __restrict__ dense_out, float* __restrict__ cpart_out, int cout0) {
  constexpr int KCin = Cin / 32;
  constexpr int NIT = 9 * KCin;
  __shared__ float red[4][64][8];
  __shared__ float scsh[2][Cin];
  __shared__ float tred[64][4];
  __shared__ float fin[64];
  int tid = threadIdx.x;
  const float inv = 1.0f / (float)(BB * NSP);

  if (cpart_in) {
    int row = tid >> 2, sl = tid & 3;
    const f32x4* cp = (const f32x4*)(cpart_in + (size_t)row * 576 + sl * 144);
    f32x4 s4 = (f32x4){0.f, 0.f, 0.f, 0.f};
#pragma unroll
    for (int j = 0; j < 36; ++j) s4 += cp[j];
    tred[row][sl] = s4.x + s4.y + s4.z + s4.w;
    __syncthreads();
    if (tid < 64) fin[tid] = tred[tid][0] + tred[tid][1] + tred[tid][2] + tred[tid][3];
    __syncthreads();
    if (blockIdx.x == 0 && blockIdx.y == 0 && tid < 32) {
      sums[Cin - 32 + tid] = fin[tid];
      sums2[Cin - 32 + tid] = fin[32 + tid];
    }
  }
  for (int ch = tid; ch < Cin; ch += 256) {
    float S, S2;
    if (cpart_in && ch >= Cin - 32) {
      S = fin[ch - (Cin - 32)];
      S2 = fin[ch - (Cin - 32) + 32];
    } else {
      S = sums[ch];
      S2 = sums2[ch];
    }
    float m = S * inv;
    float var = S2 * inv - m * m;
    float sc_ = rsqrtf(var + 1e-5f) * g[ch];
    scsh[0][ch] = sc_;
    scsh[1][ch] = bbp[ch] - m * sc_;
  }
  __syncthreads();

  int wv = tid >> 6, lane = tid & 63;
  int m15 = lane & 15, quad = lane >> 4;
  int b = blockIdx.y;
  int n0 = blockIdx.x * 16;
  int n = n0 + m15;
  int h = n / WW, w = n % WW;
  f32x4 of0 = (f32x4){0.f, 0.f, 0.f, 0.f};
  f32x4 of1 = (f32x4){0.f, 0.f, 0.f, 0.f};
  const __bf16* bx_ = x_t + (size_t)b * NSP * 128;
  const __bf16* bd_ = dense_t + (size_t)b * NSP * 128;
  const bf16x8 zf = {};
  int begin = (wv * NIT) / 4, end = ((wv + 1) * NIT) / 4;
  int cur = -1;
  float bsc[8], bsh[8];
  const __bf16* base = nullptr;
  for (int ci = begin; ci < end; ++ci) {
    int chunk = ci / 9;
    int tap = ci - chunk * 9;
    int kc = chunk * 32;
    if (chunk != cur) {
      cur = chunk;
      int cc = kc + quad * 8;
#pragma unroll
      for (int j = 0; j < 8; ++j) {
        bsc[j] = scsh[0][cc + j];
        bsh[j] = scsh[1][cc + j];
      }
      base = (cc < 128) ? (bx_ + cc) : (bd_ + cc - 128);
    }
    int dh = tap / 3 - 1, dw = tap % 3 - 1;
    bool valid = ((unsigned)(h + dh) < HH) && ((unsigned)(w + dw) < WW);
    int pa = valid ? (n + dh * WW + dw) : 0;
    bf16x8 raw = *(const bf16x8*)(base + (size_t)pa * 128);
    bf16x8 bfr;
#pragma unroll
    for (int j = 0; j < 8; ++j) {
      float v = fmaxf((float)raw[j] * bsc[j] + bsh[j], 0.0f);
      bfr[j] = (__bf16)v;
    }
    if (!valid) bfr = zf;
    const __bf16* wt = wb + (size_t)tap * 32 * Cin + kc + quad * 8;
    bf16x8 a0 = *(const bf16x8*)(wt + (size_t)m15 * Cin);
    bf16x8 a1 = *(const bf16x8*)(wt + (size_t)(16 + m15) * Cin);
    of0 = __builtin_amdgcn_mfma_f32_16x16x32_bf16(a0, bfr, of0, 0, 0, 0);
    of1 = __builtin_amdgcn_mfma_f32_16x16x32_bf16(a1, bfr, of1, 0, 0, 0);
  }
  float* myred = red[wv][lane];
#pragma unroll
  for (int reg = 0; reg < 4; ++reg) {
    myred[reg] = of0[reg];
    myred[4 + reg] = of1[reg];
  }
  __syncthreads();
  if (wv == 0) {
    int dloc = cout0 - 128;
    __bf16* dt = dense_out + ((size_t)b * NSP + n) * 128 + dloc;
    bf16x4 pk0, pk1;
    float sv[4][4];
#pragma unroll
    for (int reg = 0; reg < 4; ++reg) {
      int o = quad * 4 + reg;
      float v0 = red[0][lane][reg] + red[1][lane][reg] + red[2][lane][reg] +
                 red[3][lane][reg] + cb[o];
      float v1 = red[0][lane][4 + reg] + red[1][lane][4 + reg] + red[2][lane][4 + reg] +
                 red[3][lane][4 + reg] + cb[16 + o];
      pk0[reg] = (__bf16)v0;
      pk1[reg] = (__bf16)v1;
      sv[reg][0] = v0;
      sv[reg][1] = v0 * v0;
      sv[reg][2] = v1;
      sv[reg][3] = v1 * v1;
    }
    *(bf16x4*)(dt + quad * 4) = pk0;
    *(bf16x4*)(dt + 16 + quad * 4) = pk1;
    if (cpart_out) {
#pragma unroll
      for (int reg = 0; reg < 4; ++reg) {
        float a0 = sv[reg][0], q0 = sv[reg][1], a1 = sv[reg][2], q1 = sv[reg][3];
#pragma unroll
        for (int mk = 1; mk < 16; mk <<= 1) {
          a0 += __shfl_xor(a0, mk);
          q0 += __shfl_xor(q0, mk);
          a1 += __shfl_xor(a1, mk);
          q1 += __shfl_xor(q1, mk);
        }
        if (m15 == 0) {
          int o = quad * 4 + reg;
          int pidx = blockIdx.y * 144 + blockIdx.x;
          cpart_out[(size_t)o * 576 + pidx] = a0;
          cpart_out[(size_t)(32 + o) * 576 + pidx] = q0;
          cpart_out[(size_t)(16 + o) * 576 + pidx] = a1;
          cpart_out[(size_t)(48 + o) * 576 + pidx] = q1;
        }
      }
    }
  }
}

// ---------------- flash-LDS MFMA attention: swapped QK^T, transpose-free P (no pt buffer) ----------------
template <int CD>
__global__ __launch_bounds__(256) void attn_part_kernel(
    const __bf16* __restrict__ Qt, const __bf16* __restrict__ Kt,
    const __bf16* __restrict__ Vb, __bf16* __restrict__ Op,
    float* __restrict__ lp) {
  constexpr int NC = CD / 16;
  constexpr int KC = CD / 32;
  constexpr int KEYS = NSP / KS;  // 576
  constexpr int KP = CD + 4;
  constexpr int VP = 36;
  __shared__ __bf16 kl[32][KP];
  __shared__ __bf16 vl[CD][VP];
  int tid = threadIdx.x;
  int wv = tid >> 6, lane = tid & 63;
  int m15 = lane & 15, quad = lane >> 4;
  int b = blockIdx.y, ks = blockIdx.z;
  int n0 = blockIdx.x * 64 + wv * 16;

  bf16x8 qf[KC];
  const __bf16* qrow = Qt + ((size_t)b * NSP + n0 + m15) * CD + quad * 8;
#pragma unroll
  for (int kc = 0; kc < KC; ++kc) qf[kc] = *(const bf16x8*)(qrow + kc * 32);

  f32x4 of[NC];
#pragma unroll
  for (int i = 0; i < NC; ++i) of[i] = (f32x4){0.f, 0.f, 0.f, 0.f};
  float lsum = 0.f;

  const __bf16* Kb = Kt + (size_t)b * NSP * CD;
  const __bf16* Vbb = Vb + (size_t)b * CD * NSP;

  for (int m0 = ks * KEYS; m0 < (ks + 1) * KEYS; m0 += 32) {
    __syncthreads();
    for (int i = tid; i < 32 * CD / 8; i += 256) {
      int row = i / (CD / 8);
      int cc8 = (i % (CD / 8)) * 8;
      *(bf16x8*)&kl[row][cc8] = *(const bf16x8*)(Kb + (size_t)(m0 + row) * CD + cc8);
    }
    for (int i = tid; i < CD * 4; i += 256) {
      int ch = i / 4;
      int k8 = (i % 4) * 8;
      *(bf16x8*)&vl[ch][k8] = *(const bf16x8*)(Vbb + (size_t)ch * NSP + m0 + k8);
    }
    __syncthreads();
    f32x4 s[2];
#pragma unroll
    for (int t = 0; t < 2; ++t) {
      f32x4 acc = (f32x4){0.f, 0.f, 0.f, 0.f};
#pragma unroll
      for (int kc = 0; kc < KC; ++kc) {
        bf16x8 kf = *(const bf16x8*)&kl[t * 16 + m15][kc * 32 + quad * 8];
        acc = __builtin_amdgcn_mfma_f32_16x16x32_bf16(kf, qf[kc], acc, 0, 0, 0);
      }
      s[t] = acc;
    }
    bf16x8 pf;
#pragma unroll
    for (int t = 0; t < 2; ++t) {
#pragma unroll
      for (int r = 0; r < 4; ++r) {
        float ev = __expf(s[t][r]);
        lsum += ev;
        pf[t * 4 + r] = (__bf16)ev;
      }
    }
#pragma unroll
    for (int ct = 0; ct < NC; ++ct) {
      bf16x4 va = *(const bf16x4*)&vl[ct * 16 + m15][4 * quad];
      bf16x4 vb_ = *(const bf16x4*)&vl[ct * 16 + m15][16 + 4 * quad];
      bf16x8 vf;
#pragma unroll
      for (int j = 0; j < 4; ++j) { vf[j] = va[j]; vf[4 + j] = vb_[j]; }
      of[ct] = __builtin_amdgcn_mfma_f32_16x16x32_bf16(pf, vf, of[ct], 0, 0, 0);
    }
  }

  lsum += __shfl_xor(lsum, 16);
  lsum += __shfl_xor(lsum, 32);
  float* lpb = lp + (size_t)(ks * BB + b) * NSP + n0;
  if (quad == 0) lpb[m15] = lsum;
  __bf16* Ob = Op + (size_t)(ks * BB + b) * CD * NSP;
#pragma unroll
  for (int ct = 0; ct < NC; ++ct) {
    bf16x4 pk;
#pragma unroll
    for (int reg = 0; reg < 4; ++reg) pk[reg] = (__bf16)of[ct][reg];
    *(bf16x4*)(Ob + (size_t)(ct * 16 + m15) * NSP + n0 + quad * 4) = pk;
  }
}

// ---------------- fused combine32 + ps + QKV: comb never materialized ----------------
__global__ __launch_bounds__(256) void c32psqkv_kernel(
    const __bf16* __restrict__ Op, const float* __restrict__ lp,
    const __bf16* __restrict__ wps, const float* __restrict__ ps_b,
    const float* __restrict__ rec, const __bf16* __restrict__ wpqk,
    const float* __restrict__ pq_b, const float* __restrict__ k_b,
    const float* __restrict__ v_b, __bf16* __restrict__ Qt,
    __bf16* __restrict__ K2t, __bf16* __restrict__ V2b, float qscale) {
  __shared__ float lds[32][33];      // att1 [ch][n-local]
  __shared__ __bf16 comb[32][136];   // comb [n-local][ch], 272B rows -> 4-bank rotation
  int b = blockIdx.y;
  int n0 = blockIdx.x * 32;
  int tid = threadIdx.x;
  int nn = tid & 31, cs = tid >> 5;
  float ltot = 0.f;
#pragma unroll
  for (int ks = 0; ks < KS; ++ks) ltot += lp[(size_t)(ks * BB + b) * NSP + n0 + nn];
  float linv = 1.0f / ltot;
#pragma unroll
  for (int j = 0; j < 4; ++j) {
    int cc = cs * 4 + j;
    float s = 0.f;
#pragma unroll
    for (int ks = 0; ks < KS; ++ks)
      s += (float)Op[((size_t)(ks * BB + b) * 32 + cc) * NSP + n0 + nn];
    lds[cc][nn] = s * linv;
  }
  __syncthreads();
  // Phase B: ps (O=128, K=32) + rec -> comb (bf16, identical rounding to old comb_t)
  int wv = tid >> 6, lane = tid & 63;
  int m15 = lane & 15, quad = lane >> 4;
  int o0 = wv * 32;
  bf16x8 a0 = *(const bf16x8*)(wps + (size_t)(o0 + m15) * 32 + quad * 8);
  bf16x8 a1 = *(const bf16x8*)(wps + (size_t)(o0 + 16 + m15) * 32 + quad * 8);
#pragma unroll
  for (int t2 = 0; t2 < 2; ++t2) {
    int nl = t2 * 16 + m15;
    int n = n0 + nl;
    bf16x8 bfr;
#pragma unroll
    for (int j = 0; j < 8; ++j) bfr[j] = (__bf16)lds[quad * 8 + j][nl];
    f32x4 of0 = (f32x4){0.f, 0.f, 0.f, 0.f};
    f32x4 of1 = (f32x4){0.f, 0.f, 0.f, 0.f};
    of0 = __builtin_amdgcn_mfma_f32_16x16x32_bf16(a0, bfr, of0, 0, 0, 0);
    of1 = __builtin_amdgcn_mfma_f32_16x16x32_bf16(a1, bfr, of1, 0, 0, 0);
#pragma unroll
    for (int t = 0; t < 2; ++t) {
      f32x4 acc = t ? of1 : of0;
      bf16x4 pk;
#pragma unroll
      for (int reg = 0; reg < 4; ++reg) {
        int ol = o0 + t * 16 + quad * 4 + reg;
        float v = acc[reg] + ps_b[ol] + rec[((size_t)b * 128 + ol) * NSP + n];
        pk[reg] = (__bf16)v;
      }
      *(bf16x4*)&comb[nl][o0 + t * 16 + quad * 4] = pk;
    }
  }
  __syncthreads();
  // Phase C: QKV (O=384, K=128 from LDS comb). 4 waves x 3 o-tiles.
#pragma unroll
  for (int j = 0; j < 3; ++j) {
    int og = (wv * 3 + j) * 32;
    int seg = og >> 7;          // 0:Q 1:K 2:V
    int ol0 = og & 127;
    const __bf16* a0p = wpqk + (size_t)(og + m15) * 128 + quad * 8;
    const __bf16* a1p = wpqk + (size_t)(og + 16 + m15) * 128 + quad * 8;
#pragma unroll
    for (int t2 = 0; t2 < 2; ++t2) {
      int nl = t2 * 16 + m15;
      int n = n0 + nl;
      f32x4 of0 = (f32x4){0.f, 0.f, 0.f, 0.f};
      f32x4 of1 = (f32x4){0.f, 0.f, 0.f, 0.f};
#pragma unroll
      for (int kc = 0; kc < 128; kc += 32) {
        bf16x8 bfr = *(const bf16x8*)&comb[nl][kc + quad * 8];
        of0 = __builtin_amdgcn_mfma_f32_16x16x32_bf16(*(const bf16x8*)(a0p + kc), bfr, of0, 0, 0, 0);
        of1 = __builtin_amdgcn_mfma_f32_16x16x32_bf16(*(const bf16x8*)(a1p + kc), bfr, of1, 0, 0, 0);
      }
#pragma unroll
      for (int t = 0; t < 2; ++t) {
        f32x4 acc = t ? of1 : of0;
        if (seg == 0) {
          bf16x4 pk;
#pragma unroll
          for (int reg = 0; reg < 4; ++reg)
            pk[reg] = (__bf16)((acc[reg] + pq_b[ol0 + t * 16 + quad * 4 + reg]) * qscale);
          *(bf16x4*)(Qt + ((size_t)b * NSP + n) * 128 + ol0 + t * 16 + quad * 4) = pk;
        } else if (seg == 1) {
          bf16x4 pk;
#pragma unroll
          for (int reg = 0; reg < 4; ++reg)
            pk[reg] = (__bf16)(acc[reg] + k_b[ol0 + t * 16 + quad * 4 + reg]);
          *(bf16x4*)(K2t + ((size_t)b * NSP + n) * 128 + ol0 + t * 16 + quad * 4) = pk;
        } else {
#pragma unroll
          for (int reg = 0; reg < 4; ++reg) {
            int ol = ol0 + t * 16 + quad * 4 + reg;
            V2b[((size_t)b * 128 + ol) * NSP + n] = (__bf16)(acc[reg] + v_b[ol]);
          }
        }
      }
    }
  }
}

// ---------------- fused combine128 + FFN: x1 kept in LDS, out written directly ----------------
__global__ __launch_bounds__(256) void c128ffn_kernel(
    const __bf16* __restrict__ Op, const float* __restrict__ lp,
    const float* __restrict__ x, const __bf16* __restrict__ wfc1,
    const float* __restrict__ fc1_b, const __bf16* __restrict__ wfc2,
    const float* __restrict__ fc2_b, float* __restrict__ outp) {
  __shared__ float x1f[16][132];
  __shared__ __bf16 x1l[16][136];
  __shared__ __bf16 hl[16][520];
  int tid = threadIdx.x;
  int b = blockIdx.y;
  int n0 = blockIdx.x * 16;
  {
    int r = tid & 15, g = tid >> 4;
    float ltot = 0.f;
#pragma unroll
    for (int ks = 0; ks < KS; ++ks) ltot += lp[(size_t)(ks * BB + b) * NSP + n0 + r];
    float linv = 1.0f / ltot;
#pragma unroll
    for (int j = 0; j < 8; ++j) {
      int ch = g * 8 + j;
      float s = 0.f;
#pragma unroll
      for (int ks = 0; ks < KS; ++ks)
        s += (float)Op[((size_t)(ks * BB + b) * CC + ch) * NSP + n0 + r];
      float v = s * linv + x[((size_t)b * CC + ch) * NSP + n0 + r];
      x1f[r][ch] = v;
      x1l[r][ch] = (__bf16)v;
    }
  }
  __syncthreads();
  int wv = tid >> 6, lane = tid & 63;
  int m15 = lane & 15, quad = lane >> 4;
  bf16x8 bf[4];
#pragma unroll
  for (int kc = 0; kc < 4; ++kc) bf[kc] = *(const bf16x8*)&x1l[m15][kc * 32 + quad * 8];
#pragma unroll
  for (int j = 0; j < 4; ++j) {
    int o0 = (wv * 4 + j) * 32;
    const __bf16* a0p = wfc1 + (size_t)(o0 + m15) * 128 + quad * 8;
    const __bf16* a1p = wfc1 + (size_t)(o0 + 16 + m15) * 128 + quad * 8;
    f32x4 of0 = (f32x4){0.f, 0.f, 0.f, 0.f};
    f32x4 of1 = (f32x4){0.f, 0.f, 0.f, 0.f};
#pragma unroll
    for (int kc = 0; kc < 4; ++kc) {
      of0 = __builtin_amdgcn_mfma_f32_16x16x32_bf16(*(const bf16x8*)(a0p + kc * 32), bf[kc], of0, 0, 0, 0);
      of1 = __builtin_amdgcn_mfma_f32_16x16x32_bf16(*(const bf16x8*)(a1p + kc * 32), bf[kc], of1, 0, 0, 0);
    }
#pragma unroll
    for (int t = 0; t < 2; ++t) {
      f32x4 acc = t ? of1 : of0;
      bf16x4 pk;
#pragma unroll
      for (int reg = 0; reg < 4; ++reg) {
        float v = fmaxf(acc[reg] + fc1_b[o0 + t * 16 + quad * 4 + reg], 0.0f);
        pk[reg] = (__bf16)(v * v);
      }
      *(bf16x4*)&hl[m15][o0 + t * 16 + quad * 4] = pk;
    }
  }
  __syncthreads();
  int o0 = wv * 32;
  const __bf16* a0p = wfc2 + (size_t)(o0 + m15) * 512 + quad * 8;
  const __bf16* a1p = wfc2 + (size_t)(o0 + 16 + m15) * 512 + quad * 8;
  f32x4 of0 = (f32x4){0.f, 0.f, 0.f, 0.f};
  f32x4 of1 = (f32x4){0.f, 0.f, 0.f, 0.f};
#pragma unroll
  for (int kc = 0; kc < 512; kc += 32) {
    bf16x8 bfr = *(const bf16x8*)&hl[m15][kc + quad * 8];
    of0 = __builtin_amdgcn_mfma_f32_16x16x32_bf16(*(const bf16x8*)(a0p + kc), bfr, of0, 0, 0, 0);
    of1 = __builtin_amdgcn_mfma_f32_16x16x32_bf16(*(const bf16x8*)(a1p + kc), bfr, of1, 0, 0, 0);
  }
  int n = n0 + m15;
#pragma unroll
  for (int t = 0; t < 2; ++t) {
    f32x4 acc = t ? of1 : of0;
#pragma unroll
    for (int reg = 0; reg < 4; ++reg) {
      int ol = o0 + t * 16 + quad * 4 + reg;
      outp[((size_t)b * 128 + ol) * NSP + n] = acc[reg] + fc2_b[ol] + x1f[m15][ol];
    }
  }
}

// ---------------- host ----------------
extern "C" void kernel_launch(void* const* d_in, const int* in_sizes, int n_in,
                              void* d_out, int out_size, void* d_ws, size_t ws_size,
                              hipStream_t stream) {
  const float* x = (const float*)d_in[0];
  const float* r_w = (const float*)d_in[1];
  const float* r_b = (const float*)d_in[2];
  const float* k_w = (const float*)d_in[3];
  const float* k_b = (const float*)d_in[4];
  const float* v_w = (const float*)d_in[5];
  const float* v_b = (const float*)d_in[6];
  // d_in[7..10]: wc1/wc2 — dead code (multiplied by zeros in reference)
  const float* u = (const float*)d_in[11];
  const float* sn1_w = (const float*)d_in[12];
  const float* sn1_b = (const float*)d_in[13];
  const float* sn2_w = (const float*)d_in[14];
  const float* sn2_b = (const float*)d_in[15];
  const float* lb_w = (const float*)d_in[16];
  const float* lb_b = (const float*)d_in[17];
  const float* ld_w = (const float*)d_in[18];
  const float* ld_b = (const float*)d_in[19];
  const float* ps_w = (const float*)d_in[20];
  const float* ps_b = (const float*)d_in[21];
  const float* pq_w = (const float*)d_in[22];
  const float* pq_b = (const float*)d_in[23];
  const float* fc1_w = (const float*)d_in[24];
  const float* fc1_b = (const float*)d_in[25];
  const float* fc2_w = (const float*)d_in[26];
  const float* fc2_b = (const float*)d_in[27];
  const float* db_g[4] = {(const float*)d_in[28], (const float*)d_in[32],
                          (const float*)d_in[36], (const float*)d_in[40]};
  const float* db_b[4] = {(const float*)d_in[29], (const float*)d_in[33],
                          (const float*)d_in[37], (const float*)d_in[41]};
  const float* db_w[4] = {(const float*)d_in[30], (const float*)d_in[34],
                          (const float*)d_in[38], (const float*)d_in[42]};
  const float* db_cb[4] = {(const float*)d_in[31], (const float*)d_in[35],
                           (const float*)d_in[39], (const float*)d_in[43]};

  float* outp = (float*)d_out;           // out  (B,C,H,W)
  float* knum = outp + BCN;              // new_num = k*v
  float* kden = outp + 2 * (size_t)BCN;  // new_den = k

  float* ws = (float*)d_ws;
  // region map (f32 slots)
  const size_t F_FEATS = 0;         // cpart0/1/2 -> Op partials (KS=4 CD=128 = 2359296)
  const size_t F_REC = 4718592;     // rec f32 (1179648)
  const size_t F_V = 5898240;       // V2b bf16 (589824)
  const size_t F_R = 7077888;       // dense_t bf16 (589824)
  const size_t F_XR = 8257536;      // xrope_t bf16 -> Qt (589824)
  const size_t F_XT = 8847360;      // x_t bf16 -> K2t (589824)
  const size_t F_DFB = 9437184;     // Dfb bf16 (147456)
  const size_t F_CT = 9732096;      // Bft (upper half)
  const size_t F_LP = 10321920;     // lp f32 (KS*B*NSP = 36864)
  const size_t F_WB = 10434048;     // conv1x1 weights bf16 (282624 bf16 = 141312 slots)
  const size_t F_WB3 = 10575360;    // conv3x3 packed weights bf16 (202752 bf16 = 101376 slots)
  const size_t F_STATS = 10676736;  // sums[256] sums2[256]
  const size_t F_TAUP = 10714112;   // tau partials (1024 x 144 = 147456)
  float* sums = ws + F_STATS;
  float* sums2 = ws + F_STATS + 256;
  float* cpart0 = ws + F_FEATS;        // conv stat partials, per layer (64 x 576 each)
  float* cpart1 = cpart0 + 36864;
  float* cpart2 = cpart1 + 36864;
  float* taupart = ws + F_TAUP;
  float* lp = ws + F_LP;
  __bf16* wbase = (__bf16*)(ws + F_WB);
  __bf16* wb3 = (__bf16*)(ws + F_WB3);
  const int W_KV = 0;        // k(16384) | v(16384)
  const int W_R = 32768;     // 16384
  const int W_SN1 = 49152;   // 16384
  const int W_SN2 = 65536;   // 16384
  const int W_LBLD = 81920;  // lb(8192) | ld(8192)
  const int W_PS = 98304;    // 4096
  const int W_PQK = 102400;  // pq(16384) | k(16384) | v(16384)
  const int W_FC1 = 151552;  // 65536
  const int W_FC2 = 217088;  // 65536
  const int W3_OFF[4] = {0, 36864, 82944, 138240};

  dim3 blk(256);
  __bf16* xrope_t = (__bf16*)(ws + F_XR);
  __bf16* x_t = (__bf16*)(ws + F_XT);

  // --- prep: weight cvt + conv pack + x stats + x dual-transpose, ONE launch ---
  Prep pp;
  pp.wsrc[0] = k_w;    pp.wlen[0] = 16384; pp.woff[0] = W_KV;
  pp.wsrc[1] = v_w;    pp.wlen[1] = 16384; pp.woff[1] = W_KV + 16384;
  pp.wsrc[2] = r_w;    pp.wlen[2] = 16384; pp.woff[2] = W_R;
  pp.wsrc[3] = sn1_w;  pp.wlen[3] = 16384; pp.woff[3] = W_SN1;
  pp.wsrc[4] = sn2_w;  pp.wlen[4] = 16384; pp.woff[4] = W_SN2;
  pp.wsrc[5] = lb_w;   pp.wlen[5] = 8192;  pp.woff[5] = W_LBLD;
  pp.wsrc[6] = ld_w;   pp.wlen[6] = 8192;  pp.woff[6] = W_LBLD + 8192;
  pp.wsrc[7] = ps_w;   pp.wlen[7] = 4096;  pp.woff[7] = W_PS;
  pp.wsrc[8] = pq_w;   pp.wlen[8] = 16384; pp.woff[8] = W_PQK;
  pp.wsrc[9] = k_w;    pp.wlen[9] = 16384; pp.woff[9] = W_PQK + 16384;
  pp.wsrc[10] = v_w;   pp.wlen[10] = 16384; pp.woff[10] = W_PQK + 32768;
  pp.wsrc[11] = fc1_w; pp.wlen[11] = 65536; pp.woff[11] = W_FC1;
  pp.wsrc[12] = fc2_w; pp.wlen[12] = 65536; pp.woff[12] = W_FC2;
  for (int i = 0; i < 4; ++i) {
    pp.psrc[i] = db_w[i];
    pp.pcin[i] = 128 + 32 * i;
    pp.poff[i] = W3_OFF[i];
  }
  pp.x = x;
  pp.sums = sums;
  pp.sums2 = sums2;
  pp.x_t = x_t;
  pp.xrope_t = xrope_t;
  prep_kernel<<<dim3(256, 23), blk, 0, stream>>>(pp, wbase, wb3);

  // --- conv layer 0 + kvr in ONE launch (independent; co-scheduled via blockIdx.z) ---
  __bf16* dense_t = (__bf16*)(ws + F_R);
  conv128kvr_kernel<<<dim3(144, 4, 2), blk, 0, stream>>>(
      x_t, xrope_t, wb3 + W3_OFF[0], db_cb[0], sums, sums2, db_g[0], db_b[0],
      dense_t, cpart0,
      wbase + W_KV, wbase + W_KV + 16384, wbase + W_R,
      k_b, v_b, r_b, u, kden, knum, ws + F_REC);

  // --- dense block layers 1-3 ---
  convbn_kernel<160><<<dim3(144, 4), blk, 0, stream>>>(
      x_t, dense_t, wb3 + W3_OFF[1], db_cb[1], sums, sums2, cpart0,
      db_g[1], db_b[1], dense_t, cpart1, 160);
  convbn_kernel<192><<<dim3(144, 4), blk, 0, stream>>>(
      x_t, dense_t, wb3 + W3_OFF[2], db_cb[2], sums, sums2, cpart1,
      db_g[2], db_b[2], dense_t, cpart2, 192);
  convbn_kernel<224><<<dim3(144, 4), blk, 0, stream>>>(
      x_t, dense_t, wb3 + W3_OFF[3], db_cb[3], sums, sums2, cpart2,
      db_g[3], db_b[3], dense_t, nullptr, 224);

  // --- spike path: fused sn1+sn2 (tau partials), sf inline in lb/ld GEMM ---
  sn12_kernel<<<dim3(144, 4), blk, 0, stream>>>(
      x_t, dense_t, wbase + W_SN1, sn1_b, wbase + W_SN2, sn2_b, taupart);
  __bf16* Bft = (__bf16*)(ws + F_CT + 294912);  // upper half of F_CT region
  __bf16* Dfb = (__bf16*)(ws + F_DFB);
  lbld_sf_kernel<<<dim3(144, 4), dim3(128), 0, stream>>>(
      x_t, dense_t, taupart, wbase + W_LBLD, lb_b, ld_b, Bft, Dfb);
  __bf16* Opart = (__bf16*)(ws + F_FEATS);  // cpart dead from here
  attn_part_kernel<32><<<dim3(36, 4, KS), blk, 0, stream>>>(Bft, Bft, Dfb, Opart, lp);

  // --- fused combine32+ps+QKV (comb never hits memory) ---
  __bf16* Qt = (__bf16*)(ws + F_XR);   // xrope_t dead after kvr
  __bf16* K2t = (__bf16*)(ws + F_XT);  // x_t dead after lbld_sf
  __bf16* V2b = (__bf16*)(ws + F_V);
  c32psqkv_kernel<<<dim3(72, 4), blk, 0, stream>>>(
      Opart, lp, wbase + W_PS, ps_b, ws + F_REC, wbase + W_PQK,
      pq_b, k_b, v_b, Qt, K2t, V2b, 0.08838834764831845f);

  // --- final attention + fused combine128+FFN (x1/x1_t/h never hit memory) ---
  attn_part_kernel<128><<<dim3(36, 4, KS), blk, 0, stream>>>(Qt, K2t, V2b, Opart, lp);
  c128ffn_kernel<<<dim3(144, 4), blk, 0, stream>>>(
      Opart, lp, x, wbase + W_FC1, fc1_b, wbase + W_FC2, fc2_b, outp);
}

// Round 15
// 369.288 us; speedup vs baseline: 1.0433x; 1.0029x over previous
//
#include <hip/hip_runtime.h>
#include <math.h>

#define BB 4
#define CC 128
#define HH 48
#define WW 48
#define NSP (HH*WW)          // 2304
#define DCC 256
#define BCN (BB*CC*NSP)      // 1179648
#define KS 4                 // attention key-splits

typedef float f32x4 __attribute__((ext_vector_type(4)));
typedef __bf16 bf16x8 __attribute__((ext_vector_type(8)));
typedef __bf16 bf16x4 __attribute__((ext_vector_type(4)));

__device__ __forceinline__ float sigmf(float v) { return 1.0f / (1.0f + __expf(-v)); }

// ---------------- merged prep: weight cvt (13) + conv3x3 pack (4) + x-stats + x dual-transpose ----------------
struct Prep {
  const float* wsrc[13];
  int wlen[13];
  int woff[13];
  const float* psrc[4];
  int pcin[4];
  int poff[4];
  const float* x;
  float* sums;
  float* sums2;
  __bf16* x_t;
  __bf16* xrope_t;
};
__global__ __launch_bounds__(256) void prep_kernel(Prep a, __bf16* __restrict__ wdst,
                                                   __bf16* __restrict__ pdst) {
  __shared__ float lds[32][33];
  __shared__ float rs[4], rs2[4];
  int g = blockIdx.y;
  int idx = blockIdx.x * 256 + threadIdx.x;
  if (g < 13) {
    if (idx < a.wlen[g]) wdst[a.woff[g] + idx] = (__bf16)a.wsrc[g][idx];
  } else if (g < 17) {
    int L = g - 13;
    int cin = a.pcin[L];
    if (idx < 9 * 32 * cin) {
      int c = idx % cin;
      int o = (idx / cin) % 32;
      int tap = idx / (cin * 32);
      pdst[a.poff[L] + idx] = (__bf16)a.psrc[L][((size_t)o * cin + c) * 9 + tap];
    }
  } else if (g == 17) {
    // x-channel BN stats: one block per channel (plain stores, no atomics)
    int c = blockIdx.x;
    if (c >= 128) return;
    float s = 0.f, s2 = 0.f;
    for (int i = threadIdx.x; i < BB * NSP; i += 256) {
      int b = i / NSP, n = i % NSP;
      float v = a.x[((size_t)b * 128 + c) * NSP + n];
      s += v;
      s2 += v * v;
    }
#pragma unroll
    for (int off = 32; off > 0; off >>= 1) {
      s += __shfl_down(s, off);
      s2 += __shfl_down(s2, off);
    }
    int wid = threadIdx.x >> 6;
    if ((threadIdx.x & 63) == 0) { rs[wid] = s; rs2[wid] = s2; }
    __syncthreads();
    if (threadIdx.x == 0) {
      a.sums[c] = rs[0] + rs[1] + rs[2] + rs[3];
      a.sums2[c] = rs2[0] + rs2[1] + rs2[2] + rs2[3];
    }
  } else {
    // dual transpose x -> x_t (plain) + xrope_t (RoPE), LDS-tiled
    int T = (g - 18) * 256 + blockIdx.x;
    if (T >= 1152) return;
    int b = T / 288;
    int r = T % 288;
    int c0 = (r / 72) * 32;
    int n0 = (r % 72) * 32;
    int tid = threadIdx.x;
    int nn = tid & 31, cs = tid >> 5;
#pragma unroll
    for (int j = 0; j < 4; ++j) {
      int cc = c0 + cs * 4 + j;
      lds[cs * 4 + j][nn] = a.x[((size_t)b * 128 + cc) * NSP + n0 + nn];
    }
    __syncthreads();
    int c = tid & 31, ns = tid >> 5;
#pragma unroll
    for (int j = 0; j < 4; ++j) {
      int n2 = ns * 4 + j;
      float pv = lds[c][n2];
      a.x_t[((size_t)b * NSP + n0 + n2) * 128 + c0 + c] = (__bf16)pv;
      int gc = c0 + c;
      int i = gc >> 1;
      float re = lds[c & ~1][n2];
      float im = lds[c | 1][n2];
      int n = n0 + n2;
      int h = n / WW, w = n % WW;
      float theta = __expf(-9.2103403719761836f * ((float)i) / 64.0f);
      float pos = (float)(h + w) * theta;
      float cs_ = cosf(pos), sn_ = sinf(pos);
      float vr_ = (gc & 1) ? (re * sn_ + im * cs_) : (re * cs_ - im * sn_);
      a.xrope_t[((size_t)b * NSP + n0 + n2) * 128 + c0 + c] = (__bf16)vr_;
    }
  }
}

// ---------------- combined conv-layer-0 + kvr (independent work, one launch) ----------------
// blockIdx.z == 0: conv3x3 layer 0 (Cin=128, inline BN from sums).  z == 1: k|v|r GEMM + rwkv.
__global__ __launch_bounds__(256) void conv128kvr_kernel(
    const __bf16* __restrict__ x_t, const __bf16* __restrict__ xrope_t,
    const __bf16* __restrict__ wb, const float* __restrict__ cb,
    const float* __restrict__ sums, const float* __restrict__ sums2,
    const float* __restrict__ g, const float* __restrict__ bbp,
    __bf16* __restrict__ dense_out, float* __restrict__ cpart_out,
    const __bf16* __restrict__ wk, const __bf16* __restrict__ wvp,
    const __bf16* __restrict__ wr,
    const float* __restrict__ k_b, const float* __restrict__ v_b,
    const float* __restrict__ r_b, const float* __restrict__ u,
    float* __restrict__ kden, float* __restrict__ knum, float* __restrict__ rec) {
  int tid = threadIdx.x;
  int wv = tid >> 6, lane = tid & 63;
  int m15 = lane & 15, quad = lane >> 4;
  int b = blockIdx.y;
  int n0 = blockIdx.x * 16;
  int n = n0 + m15;

  if (blockIdx.z == 1) {
    // ---- kvr path ----
    int o0 = wv * 32;
    const __bf16* brr = xrope_t + ((size_t)b * NSP + n) * 128 + quad * 8;
    const __bf16* brx = x_t + ((size_t)b * NSP + n) * 128 + quad * 8;
    const __bf16* ak0 = wk + (size_t)(o0 + m15) * 128 + quad * 8;
    const __bf16* ak1 = wk + (size_t)(o0 + 16 + m15) * 128 + quad * 8;
    const __bf16* av0 = wvp + (size_t)(o0 + m15) * 128 + quad * 8;
    const __bf16* av1 = wvp + (size_t)(o0 + 16 + m15) * 128 + quad * 8;
    const __bf16* ar0 = wr + (size_t)(o0 + m15) * 128 + quad * 8;
    const __bf16* ar1 = wr + (size_t)(o0 + 16 + m15) * 128 + quad * 8;
    f32x4 fk[2], fv[2], fr[2];
#pragma unroll
    for (int t = 0; t < 2; ++t) {
      fk[t] = (f32x4){0.f, 0.f, 0.f, 0.f};
      fv[t] = (f32x4){0.f, 0.f, 0.f, 0.f};
      fr[t] = (f32x4){0.f, 0.f, 0.f, 0.f};
    }
#pragma unroll
    for (int kc = 0; kc < 128; kc += 32) {
      bf16x8 br_ = *(const bf16x8*)(brr + kc);
      bf16x8 bx_ = *(const bf16x8*)(brx + kc);
      fk[0] = __builtin_amdgcn_mfma_f32_16x16x32_bf16(*(const bf16x8*)(ak0 + kc), br_, fk[0], 0, 0, 0);
      fk[1] = __builtin_amdgcn_mfma_f32_16x16x32_bf16(*(const bf16x8*)(ak1 + kc), br_, fk[1], 0, 0, 0);
      fv[0] = __builtin_amdgcn_mfma_f32_16x16x32_bf16(*(const bf16x8*)(av0 + kc), br_, fv[0], 0, 0, 0);
      fv[1] = __builtin_amdgcn_mfma_f32_16x16x32_bf16(*(const bf16x8*)(av1 + kc), br_, fv[1], 0, 0, 0);
      fr[0] = __builtin_amdgcn_mfma_f32_16x16x32_bf16(*(const bf16x8*)(ar0 + kc), bx_, fr[0], 0, 0, 0);
      fr[1] = __builtin_amdgcn_mfma_f32_16x16x32_bf16(*(const bf16x8*)(ar1 + kc), bx_, fr[1], 0, 0, 0);
    }
#pragma unroll
    for (int t = 0; t < 2; ++t) {
#pragma unroll
      for (int reg = 0; reg < 4; ++reg) {
        int ol = o0 + t * 16 + quad * 4 + reg;
        float kk = fk[t][reg] + k_b[ol];
        float vv = fv[t][reg] + v_b[ol];
        float rr = sigmf(fr[t][reg] + r_b[ol]);
        float eu = __expf(u[ol]);
        size_t idx = ((size_t)b * 128 + ol) * NSP + n;
        float nv = kk * vv, tt = eu * kk;
        kden[idx] = kk;
        knum[idx] = nv;
        rec[idx] = rr * ((nv + tt * vv) / (kk + tt));
      }
    }
    return;
  }

  // ---- conv layer 0 path (Cin=128) ----
  constexpr int Cin = 128;
  constexpr int NIT = 9 * (Cin / 32);
  __shared__ float red[4][64][8];
  __shared__ float scsh[2][Cin];
  const float inv = 1.0f / (float)(BB * NSP);
  for (int ch = tid; ch < Cin; ch += 256) {
    float m = sums[ch] * inv;
    float var = sums2[ch] * inv - m * m;
    float sc_ = rsqrtf(var + 1e-5f) * g[ch];
    scsh[0][ch] = sc_;
    scsh[1][ch] = bbp[ch] - m * sc_;
  }
  __syncthreads();

  int h = n / WW, w = n % WW;
  f32x4 of0 = (f32x4){0.f, 0.f, 0.f, 0.f};
  f32x4 of1 = (f32x4){0.f, 0.f, 0.f, 0.f};
  const __bf16* bx_ = x_t + (size_t)b * NSP * 128;
  const bf16x8 zf = {};
  int begin = (wv * NIT) / 4, end = ((wv + 1) * NIT) / 4;
  int cur = -1;
  float bsc[8], bsh[8];
  const __bf16* base = nullptr;
  for (int ci = begin; ci < end; ++ci) {
    int chunk = ci / 9;
    int tap = ci - chunk * 9;
    int kc = chunk * 32;
    if (chunk != cur) {
      cur = chunk;
      int cc = kc + quad * 8;
#pragma unroll
      for (int j = 0; j < 8; ++j) {
        bsc[j] = scsh[0][cc + j];
        bsh[j] = scsh[1][cc + j];
      }
      base = bx_ + cc;
    }
    int dh = tap / 3 - 1, dw = tap % 3 - 1;
    bool valid = ((unsigned)(h + dh) < HH) && ((unsigned)(w + dw) < WW);
    int pa = valid ? (n + dh * WW + dw) : 0;
    bf16x8 raw = *(const bf16x8*)(base + (size_t)pa * 128);
    bf16x8 bfr;
#pragma unroll
    for (int j = 0; j < 8; ++j) {
      float v = fmaxf((float)raw[j] * bsc[j] + bsh[j], 0.0f);
      bfr[j] = (__bf16)v;
    }
    if (!valid) bfr = zf;
    const __bf16* wt = wb + (size_t)tap * 32 * Cin + kc + quad * 8;
    bf16x8 a0 = *(const bf16x8*)(wt + (size_t)m15 * Cin);
    bf16x8 a1 = *(const bf16x8*)(wt + (size_t)(16 + m15) * Cin);
    of0 = __builtin_amdgcn_mfma_f32_16x16x32_bf16(a0, bfr, of0, 0, 0, 0);
    of1 = __builtin_amdgcn_mfma_f32_16x16x32_bf16(a1, bfr, of1, 0, 0, 0);
  }
  float* myred = red[wv][lane];
#pragma unroll
  for (int reg = 0; reg < 4; ++reg) {
    myred[reg] = of0[reg];
    myred[4 + reg] = of1[reg];
  }
  __syncthreads();
  if (wv == 0) {
    __bf16* dt = dense_out + ((size_t)b * NSP + n) * 128;  // cout0=128 -> dloc 0
    bf16x4 pk0, pk1;
    float sv[4][4];
#pragma unroll
    for (int reg = 0; reg < 4; ++reg) {
      int o = quad * 4 + reg;
      float v0 = red[0][lane][reg] + red[1][lane][reg] + red[2][lane][reg] +
                 red[3][lane][reg] + cb[o];
      float v1 = red[0][lane][4 + reg] + red[1][lane][4 + reg] + red[2][lane][4 + reg] +
                 red[3][lane][4 + reg] + cb[16 + o];
      pk0[reg] = (__bf16)v0;
      pk1[reg] = (__bf16)v1;
      sv[reg][0] = v0;
      sv[reg][1] = v0 * v0;
      sv[reg][2] = v1;
      sv[reg][3] = v1 * v1;
    }
    *(bf16x4*)(dt + quad * 4) = pk0;
    *(bf16x4*)(dt + 16 + quad * 4) = pk1;
#pragma unroll
    for (int reg = 0; reg < 4; ++reg) {
      float a0 = sv[reg][0], q0 = sv[reg][1], a1 = sv[reg][2], q1 = sv[reg][3];
#pragma unroll
      for (int mk = 1; mk < 16; mk <<= 1) {
        a0 += __shfl_xor(a0, mk);
        q0 += __shfl_xor(q0, mk);
        a1 += __shfl_xor(a1, mk);
        q1 += __shfl_xor(q1, mk);
      }
      if (m15 == 0) {
        int o = quad * 4 + reg;
        int pidx = blockIdx.y * 144 + blockIdx.x;
        cpart_out[(size_t)o * 576 + pidx] = a0;
        cpart_out[(size_t)(32 + o) * 576 + pidx] = q0;
        cpart_out[(size_t)(16 + o) * 576 + pidx] = a1;
        cpart_out[(size_t)(48 + o) * 576 + pidx] = q1;
      }
    }
  }
}

// ---------------- fused sn1+sn2: z1 kept in LDS, tau partials out ----------------
__global__ __launch_bounds__(256) void sn12_kernel(
    const __bf16* __restrict__ x_t, const __bf16* __restrict__ dense_t,
    const __bf16* __restrict__ wsn1, const float* __restrict__ sn1_b,
    const __bf16* __restrict__ wsn2, const float* __restrict__ sn2_b,
    float* __restrict__ taupart) {
  __shared__ __bf16 z1l[16][72];
  int tid = threadIdx.x;
  int wv = tid >> 6, lane = tid & 63;
  int m15 = lane & 15, quad = lane >> 4;
  int b = blockIdx.y;
  int n0 = blockIdx.x * 16;
  int n = n0 + m15;
  if (wv < 2) {
    int o0 = wv * 32;
    const __bf16* bx = x_t + ((size_t)b * NSP + n) * 128 + quad * 8;
    const __bf16* bd = dense_t + ((size_t)b * NSP + n) * 128 + quad * 8;
    const __bf16* a0p = wsn1 + (size_t)(o0 + m15) * 256 + quad * 8;
    const __bf16* a1p = wsn1 + (size_t)(o0 + 16 + m15) * 256 + quad * 8;
    f32x4 of0 = (f32x4){0.f, 0.f, 0.f, 0.f};
    f32x4 of1 = (f32x4){0.f, 0.f, 0.f, 0.f};
#pragma unroll
    for (int kc = 0; kc < 256; kc += 32) {
      bf16x8 bfr = (kc < 128) ? *(const bf16x8*)(bx + kc) : *(const bf16x8*)(bd + (kc - 128));
      bf16x8 a0 = *(const bf16x8*)(a0p + kc);
      bf16x8 a1 = *(const bf16x8*)(a1p + kc);
      of0 = __builtin_amdgcn_mfma_f32_16x16x32_bf16(a0, bfr, of0, 0, 0, 0);
      of1 = __builtin_amdgcn_mfma_f32_16x16x32_bf16(a1, bfr, of1, 0, 0, 0);
    }
#pragma unroll
    for (int t = 0; t < 2; ++t) {
      f32x4 acc = t ? of1 : of0;
#pragma unroll
      for (int reg = 0; reg < 4; ++reg) {
        int ol = o0 + t * 16 + quad * 4 + reg;
        z1l[m15][ol] = (__bf16)fmaxf(acc[reg] + sn1_b[ol], 0.0f);
      }
    }
  }
  __syncthreads();
  bf16x8 bfr0 = *(const bf16x8*)&z1l[m15][quad * 8];
  bf16x8 bfr1 = *(const bf16x8*)&z1l[m15][32 + quad * 8];
#pragma unroll
  for (int ot = 0; ot < 2; ++ot) {
    int o0 = (wv * 2 + ot) * 32;
    const __bf16* a0p = wsn2 + (size_t)(o0 + m15) * 64 + quad * 8;
    const __bf16* a1p = wsn2 + (size_t)(o0 + 16 + m15) * 64 + quad * 8;
    f32x4 of0 = (f32x4){0.f, 0.f, 0.f, 0.f};
    f32x4 of1 = (f32x4){0.f, 0.f, 0.f, 0.f};
    of0 = __builtin_amdgcn_mfma_f32_16x16x32_bf16(*(const bf16x8*)(a0p), bfr0, of0, 0, 0, 0);
    of0 = __builtin_amdgcn_mfma_f32_16x16x32_bf16(*(const bf16x8*)(a0p + 32), bfr1, of0, 0, 0, 0);
    of1 = __builtin_amdgcn_mfma_f32_16x16x32_bf16(*(const bf16x8*)(a1p), bfr0, of1, 0, 0, 0);
    of1 = __builtin_amdgcn_mfma_f32_16x16x32_bf16(*(const bf16x8*)(a1p + 32), bfr1, of1, 0, 0, 0);
#pragma unroll
    for (int t = 0; t < 2; ++t) {
      f32x4 acc = t ? of1 : of0;
#pragma unroll
      for (int reg = 0; reg < 4; ++reg) {
        int ol = o0 + t * 16 + quad * 4 + reg;
        float sv = sigmf(acc[reg] + sn2_b[ol]);
        sv += __shfl_xor(sv, 1);
        sv += __shfl_xor(sv, 2);
        sv += __shfl_xor(sv, 4);
        sv += __shfl_xor(sv, 8);
        if (m15 == 0)
          taupart[((size_t)(b * DCC + ol)) * 144 + blockIdx.x] = sv;
      }
    }
  }
}

// ---------------- lb|ld GEMM with inline spike-fn B (sf never materialized) ----------------
__global__ __launch_bounds__(128) void lbld_sf_kernel(
    const __bf16* __restrict__ x_t, const __bf16* __restrict__ dense_t,
    const float* __restrict__ taupart, const __bf16* __restrict__ wlb,
    const float* __restrict__ lb_b, const float* __restrict__ ld_b,
    __bf16* __restrict__ Bft, __bf16* __restrict__ Dfb) {
  __shared__ float ef[256];
  int tid = threadIdx.x;
  int b = blockIdx.y;
  for (int ch = tid; ch < 256; ch += 128) {
    const f32x4* tp = (const f32x4*)(taupart + ((size_t)(b * DCC + ch)) * 144);
    f32x4 s4 = (f32x4){0.f, 0.f, 0.f, 0.f};
#pragma unroll
    for (int j = 0; j < 36; ++j) s4 += tp[j];
    float tv = (s4.x + s4.y + s4.z + s4.w) * (1.0f / (float)NSP);
    ef[ch] = __expf(-1.0f / (tv + 1e-6f)) - 1.0f;
  }
  __syncthreads();
  int wv = tid >> 6, lane = tid & 63;
  int m15 = lane & 15, quad = lane >> 4;
  int n0 = blockIdx.x * 16;
  int o0 = wv * 32;
  int n = n0 + m15;
  const __bf16* bx = x_t + ((size_t)b * NSP + n) * 128 + quad * 8;
  const __bf16* bd = dense_t + ((size_t)b * NSP + n) * 128 + quad * 8;
  const __bf16* a0p = wlb + (size_t)(o0 + m15) * 256 + quad * 8;
  const __bf16* a1p = wlb + (size_t)(o0 + 16 + m15) * 256 + quad * 8;
  f32x4 of0 = (f32x4){0.f, 0.f, 0.f, 0.f};
  f32x4 of1 = (f32x4){0.f, 0.f, 0.f, 0.f};
#pragma unroll
  for (int kc = 0; kc < 256; kc += 32) {
    bf16x8 raw = (kc < 128) ? *(const bf16x8*)(bx + kc) : *(const bf16x8*)(bd + (kc - 128));
    bf16x8 sfv;
#pragma unroll
    for (int j = 0; j < 8; ++j) {
      float df = (float)raw[j];
      float sp = sigmf((df - 1.0f) * 5.0f);
      sfv[j] = (__bf16)(df * (1.0f + sp * ef[kc + quad * 8 + j]));
    }
    bf16x8 a0 = *(const bf16x8*)(a0p + kc);
    bf16x8 a1 = *(const bf16x8*)(a1p + kc);
    of0 = __builtin_amdgcn_mfma_f32_16x16x32_bf16(a0, sfv, of0, 0, 0, 0);
    of1 = __builtin_amdgcn_mfma_f32_16x16x32_bf16(a1, sfv, of1, 0, 0, 0);
  }
  if (o0 == 0) {
#pragma unroll
    for (int t = 0; t < 2; ++t) {
      f32x4 acc = t ? of1 : of0;
      bf16x4 pk;
#pragma unroll
      for (int reg = 0; reg < 4; ++reg) pk[reg] = (__bf16)(acc[reg] + lb_b[t * 16 + quad * 4 + reg]);
      *(bf16x4*)(Bft + ((size_t)b * NSP + n) * 32 + t * 16 + quad * 4) = pk;
    }
  } else {
#pragma unroll
    for (int t = 0; t < 2; ++t) {
      f32x4 acc = t ? of1 : of0;
#pragma unroll
      for (int reg = 0; reg < 4; ++reg) {
        int ol = t * 16 + quad * 4 + reg;
        Dfb[((size_t)b * 32 + ol) * NSP + n] = (__bf16)(acc[reg] + ld_b[ol]);
      }
    }
  }
}

// ---------------- conv3x3 with inline BN+ReLU on the B-load ----------------
template <int Cin>
__global__ __launch_bounds__(256) void convbn_kernel(
    const __bf16* __restrict__ x_t, const __bf16* __restrict__ dense_t,
    const __bf16* __restrict__ wb, const float* __restrict__ cb,
    float* __restrict__ sums, float* __restrict__ sums2,
    const float* __restrict__ cpart_in,
    const float* __restrict__ g, const float* __restrict__ bbp,
    __bf16* __restrict__ dense_out, float* __restrict__ cpart_out, int cout0) {
  constexpr int KCin = Cin / 32;
  constexpr int NIT = 9 * KCin;
  __shared__ float red[4][64][8];
  __shared__ float scsh[2][Cin];
  __shared__ float tred[64][4];
  __shared__ float fin[64];
  int tid = threadIdx.x;
  const float inv = 1.0f / (float)(BB * NSP);

  if (cpart_in) {
    int row = tid >> 2, sl = tid & 3;
    const f32x4* cp = (const f32x4*)(cpart_in + (size_t)row * 576 + sl * 144);
    f32x4 s4 = (f32x4){0.f, 0.f, 0.f, 0.f};
#pragma unroll
    for (int j = 0; j < 36; ++j) s4 += cp[j];
    tred[row][sl] = s4.x + s4.y + s4.z + s4.w;
    __syncthreads();
    if (tid < 64) fin[tid] = tred[tid][0] + tred[tid][1] + tred[tid][2] + tred[tid][3];
    __syncthreads();
    if (blockIdx.x == 0 && blockIdx.y == 0 && tid < 32) {
      sums[Cin - 32 + tid] = fin[tid];
      sums2[Cin - 32 + tid] = fin[32 + tid];
    }
  }
  for (int ch = tid; ch < Cin; ch += 256) {
    float S, S2;
    if (cpart_in && ch >= Cin - 32) {
      S = fin[ch - (Cin - 32)];
      S2 = fin[ch - (Cin - 32) + 32];
    } else {
      S = sums[ch];
      S2 = sums2[ch];
    }
    float m = S * inv;
    float var = S2 * inv - m * m;
    float sc_ = rsqrtf(var + 1e-5f) * g[ch];
    scsh[0][ch] = sc_;
    scsh[1][ch] = bbp[ch] - m * sc_;
  }
  __syncthreads();

  int wv = tid >> 6, lane = tid & 63;
  int m15 = lane & 15, quad = lane >> 4;
  int b = blockIdx.y;
  int n0 = blockIdx.x * 16;
  int n = n0 + m15;
  int h = n / WW, w = n % WW;
  f32x4 of0 = (f32x4){0.f, 0.f, 0.f, 0.f};
  f32x4 of1 = (f32x4){0.f, 0.f, 0.f, 0.f};
  const __bf16* bx_ = x_t + (size_t)b * NSP * 128;
  const __bf16* bd_ = dense_t + (size_t)b * NSP * 128;
  const bf16x8 zf = {};
  int begin = (wv * NIT) / 4, end = ((wv + 1) * NIT) / 4;
  int cur = -1;
  float bsc[8], bsh[8];
  const __bf16* base = nullptr;
  for (int ci = begin; ci < end; ++ci) {
    int chunk = ci / 9;
    int tap = ci - chunk * 9;
    int kc = chunk * 32;
    if (chunk != cur) {
      cur = chunk;
      int cc = kc + quad * 8;
#pragma unroll
      for (int j = 0; j < 8; ++j) {
        bsc[j] = scsh[0][cc + j];
        bsh[j] = scsh[1][cc + j];
      }
      base = (cc < 128) ? (bx_ + cc) : (bd_ + cc - 128);
    }
    int dh = tap / 3 - 1, dw = tap % 3 - 1;
    bool valid = ((unsigned)(h + dh) < HH) && ((unsigned)(w + dw) < WW);
    int pa = valid ? (n + dh * WW + dw) : 0;
    bf16x8 raw = *(const bf16x8*)(base + (size_t)pa * 128);
    bf16x8 bfr;
#pragma unroll
    for (int j = 0; j < 8; ++j) {
      float v = fmaxf((float)raw[j] * bsc[j] + bsh[j], 0.0f);
      bfr[j] = (__bf16)v;
    }
    if (!valid) bfr = zf;
    const __bf16* wt = wb + (size_t)tap * 32 * Cin + kc + quad * 8;
    bf16x8 a0 = *(const bf16x8*)(wt + (size_t)m15 * Cin);
    bf16x8 a1 = *(const bf16x8*)(wt + (size_t)(16 + m15) * Cin);
    of0 = __builtin_amdgcn_mfma_f32_16x16x32_bf16(a0, bfr, of0, 0, 0, 0);
    of1 = __builtin_amdgcn_mfma_f32_16x16x32_bf16(a1, bfr, of1, 0, 0, 0);
  }
  float* myred = red[wv][lane];
#pragma unroll
  for (int reg = 0; reg < 4; ++reg) {
    myred[reg] = of0[reg];
    myred[4 + reg] = of1[reg];
  }
  __syncthreads();
  if (wv == 0) {
    int dloc = cout0 - 128;
    __bf16* dt = dense_out + ((size_t)b * NSP + n) * 128 + dloc;
    bf16x4 pk0, pk1;
    float sv[4][4];
#pragma unroll
    for (int reg = 0; reg < 4; ++reg) {
      int o = quad * 4 + reg;
      float v0 = red[0][lane][reg] + red[1][lane][reg] + red[2][lane][reg] +
                 red[3][lane][reg] + cb[o];
      float v1 = red[0][lane][4 + reg] + red[1][lane][4 + reg] + red[2][lane][4 + reg] +
                 red[3][lane][4 + reg] + cb[16 + o];
      pk0[reg] = (__bf16)v0;
      pk1[reg] = (__bf16)v1;
      sv[reg][0] = v0;
      sv[reg][1] = v0 * v0;
      sv[reg][2] = v1;
      sv[reg][3] = v1 * v1;
    }
    *(bf16x4*)(dt + quad * 4) = pk0;
    *(bf16x4*)(dt + 16 + quad * 4) = pk1;
    if (cpart_out) {
#pragma unroll
      for (int reg = 0; reg < 4; ++reg) {
        float a0 = sv[reg][0], q0 = sv[reg][1], a1 = sv[reg][2], q1 = sv[reg][3];
#pragma unroll
        for (int mk = 1; mk < 16; mk <<= 1) {
          a0 += __shfl_xor(a0, mk);
          q0 += __shfl_xor(q0, mk);
          a1 += __shfl_xor(a1, mk);
          q1 += __shfl_xor(q1, mk);
        }
        if (m15 == 0) {
          int o = quad * 4 + reg;
          int pidx = blockIdx.y * 144 + blockIdx.x;
          cpart_out[(size_t)o * 576 + pidx] = a0;
          cpart_out[(size_t)(32 + o) * 576 + pidx] = q0;
          cpart_out[(size_t)(16 + o) * 576 + pidx] = a1;
          cpart_out[(size_t)(48 + o) * 576 + pidx] = q1;
        }
      }
    }
  }
}

// ---------------- flash-LDS MFMA attention: swapped QK^T, 64-key tiles (half the barriers) ----------------
// Per 64-key tile: one stage + one barrier pair; compute in two 32-key halves (identical FP order
// to the previous 32-key-tile version).
template <int CD>
__global__ __launch_bounds__(256) void attn_part_kernel(
    const __bf16* __restrict__ Qt, const __bf16* __restrict__ Kt,
    const __bf16* __restrict__ Vb, __bf16* __restrict__ Op,
    float* __restrict__ lp) {
  constexpr int NC = CD / 16;
  constexpr int KC = CD / 32;
  constexpr int KEYS = NSP / KS;  // 576 = 9 x 64
  constexpr int KP = CD + 4;
  constexpr int VP = 68;          // 64 keys + 4 pad
  __shared__ __bf16 kl[64][KP];
  __shared__ __bf16 vl[CD][VP];
  int tid = threadIdx.x;
  int wv = tid >> 6, lane = tid & 63;
  int m15 = lane & 15, quad = lane >> 4;
  int b = blockIdx.y, ks = blockIdx.z;
  int n0 = blockIdx.x * 64 + wv * 16;

  bf16x8 qf[KC];
  const __bf16* qrow = Qt + ((size_t)b * NSP + n0 + m15) * CD + quad * 8;
#pragma unroll
  for (int kc = 0; kc < KC; ++kc) qf[kc] = *(const bf16x8*)(qrow + kc * 32);

  f32x4 of[NC];
#pragma unroll
  for (int i = 0; i < NC; ++i) of[i] = (f32x4){0.f, 0.f, 0.f, 0.f};
  float lsum = 0.f;

  const __bf16* Kb = Kt + (size_t)b * NSP * CD;
  const __bf16* Vbb = Vb + (size_t)b * CD * NSP;

  for (int m0 = ks * KEYS; m0 < (ks + 1) * KEYS; m0 += 64) {
    __syncthreads();
    for (int i = tid; i < 64 * CD / 8; i += 256) {
      int row = i / (CD / 8);
      int cc8 = (i % (CD / 8)) * 8;
      *(bf16x8*)&kl[row][cc8] = *(const bf16x8*)(Kb + (size_t)(m0 + row) * CD + cc8);
    }
    for (int i = tid; i < CD * 8; i += 256) {
      int ch = i / 8;
      int k8 = (i % 8) * 8;
      *(bf16x8*)&vl[ch][k8] = *(const bf16x8*)(Vbb + (size_t)ch * NSP + m0 + k8);
    }
    __syncthreads();
#pragma unroll
    for (int half = 0; half < 2; ++half) {
      int kb = half * 32;
      f32x4 s[2];
#pragma unroll
      for (int t = 0; t < 2; ++t) {
        f32x4 acc = (f32x4){0.f, 0.f, 0.f, 0.f};
#pragma unroll
        for (int kc = 0; kc < KC; ++kc) {
          bf16x8 kf = *(const bf16x8*)&kl[kb + t * 16 + m15][kc * 32 + quad * 8];
          acc = __builtin_amdgcn_mfma_f32_16x16x32_bf16(kf, qf[kc], acc, 0, 0, 0);
        }
        s[t] = acc;
      }
      bf16x8 pf;
#pragma unroll
      for (int t = 0; t < 2; ++t) {
#pragma unroll
        for (int r = 0; r < 4; ++r) {
          float ev = __expf(s[t][r]);
          lsum += ev;
          pf[t * 4 + r] = (__bf16)ev;
        }
      }
#pragma unroll
      for (int ct = 0; ct < NC; ++ct) {
        bf16x4 va = *(const bf16x4*)&vl[ct * 16 + m15][kb + 4 * quad];
        bf16x4 vb_ = *(const bf16x4*)&vl[ct * 16 + m15][kb + 16 + 4 * quad];
        bf16x8 vf;
#pragma unroll
        for (int j = 0; j < 4; ++j) { vf[j] = va[j]; vf[4 + j] = vb_[j]; }
        of[ct] = __builtin_amdgcn_mfma_f32_16x16x32_bf16(pf, vf, of[ct], 0, 0, 0);
      }
    }
  }

  lsum += __shfl_xor(lsum, 16);
  lsum += __shfl_xor(lsum, 32);
  float* lpb = lp + (size_t)(ks * BB + b) * NSP + n0;
  if (quad == 0) lpb[m15] = lsum;
  __bf16* Ob = Op + (size_t)(ks * BB + b) * CD * NSP;
#pragma unroll
  for (int ct = 0; ct < NC; ++ct) {
    bf16x4 pk;
#pragma unroll
    for (int reg = 0; reg < 4; ++reg) pk[reg] = (__bf16)of[ct][reg];
    *(bf16x4*)(Ob + (size_t)(ct * 16 + m15) * NSP + n0 + quad * 4) = pk;
  }
}

// ---------------- fused combine32 + ps + QKV: comb never materialized ----------------
__global__ __launch_bounds__(256) void c32psqkv_kernel(
    const __bf16* __restrict__ Op, const float* __restrict__ lp,
    const __bf16* __restrict__ wps, const float* __restrict__ ps_b,
    const float* __restrict__ rec, const __bf16* __restrict__ wpqk,
    const float* __restrict__ pq_b, const float* __restrict__ k_b,
    const float* __restrict__ v_b, __bf16* __restrict__ Qt,
    __bf16* __restrict__ K2t, __bf16* __restrict__ V2b, float qscale) {
  __shared__ float lds[32][33];      // att1 [ch][n-local]
  __shared__ __bf16 comb[32][136];   // comb [n-local][ch], 272B rows -> 4-bank rotation
  int b = blockIdx.y;
  int n0 = blockIdx.x * 32;
  int tid = threadIdx.x;
  int nn = tid & 31, cs = tid >> 5;
  float ltot = 0.f;
#pragma unroll
  for (int ks = 0; ks < KS; ++ks) ltot += lp[(size_t)(ks * BB + b) * NSP + n0 + nn];
  float linv = 1.0f / ltot;
#pragma unroll
  for (int j = 0; j < 4; ++j) {
    int cc = cs * 4 + j;
    float s = 0.f;
#pragma unroll
    for (int ks = 0; ks < KS; ++ks)
      s += (float)Op[((size_t)(ks * BB + b) * 32 + cc) * NSP + n0 + nn];
    lds[cc][nn] = s * linv;
  }
  __syncthreads();
  // Phase B: ps (O=128, K=32) + rec -> comb (bf16, identical rounding to old comb_t)
  int wv = tid >> 6, lane = tid & 63;
  int m15 = lane & 15, quad = lane >> 4;
  int o0 = wv * 32;
  bf16x8 a0 = *(const bf16x8*)(wps + (size_t)(o0 + m15) * 32 + quad * 8);
  bf16x8 a1 = *(const bf16x8*)(wps + (size_t)(o0 + 16 + m15) * 32 + quad * 8);
#pragma unroll
  for (int t2 = 0; t2 < 2; ++t2) {
    int nl = t2 * 16 + m15;
    int n = n0 + nl;
    bf16x8 bfr;
#pragma unroll
    for (int j = 0; j < 8; ++j) bfr[j] = (__bf16)lds[quad * 8 + j][nl];
    f32x4 of0 = (f32x4){0.f, 0.f, 0.f, 0.f};
    f32x4 of1 = (f32x4){0.f, 0.f, 0.f, 0.f};
    of0 = __builtin_amdgcn_mfma_f32_16x16x32_bf16(a0, bfr, of0, 0, 0, 0);
    of1 = __builtin_amdgcn_mfma_f32_16x16x32_bf16(a1, bfr, of1, 0, 0, 0);
#pragma unroll
    for (int t = 0; t < 2; ++t) {
      f32x4 acc = t ? of1 : of0;
      bf16x4 pk;
#pragma unroll
      for (int reg = 0; reg < 4; ++reg) {
        int ol = o0 + t * 16 + quad * 4 + reg;
        float v = acc[reg] + ps_b[ol] + rec[((size_t)b * 128 + ol) * NSP + n];
        pk[reg] = (__bf16)v;
      }
      *(bf16x4*)&comb[nl][o0 + t * 16 + quad * 4] = pk;
    }
  }
  __syncthreads();
  // Phase C: QKV (O=384, K=128 from LDS comb). 4 waves x 3 o-tiles.
#pragma unroll
  for (int j = 0; j < 3; ++j) {
    int og = (wv * 3 + j) * 32;
    int seg = og >> 7;          // 0:Q 1:K 2:V
    int ol0 = og & 127;
    const __bf16* a0p = wpqk + (size_t)(og + m15) * 128 + quad * 8;
    const __bf16* a1p = wpqk + (size_t)(og + 16 + m15) * 128 + quad * 8;
#pragma unroll
    for (int t2 = 0; t2 < 2; ++t2) {
      int nl = t2 * 16 + m15;
      int n = n0 + nl;
      f32x4 of0 = (f32x4){0.f, 0.f, 0.f, 0.f};
      f32x4 of1 = (f32x4){0.f, 0.f, 0.f, 0.f};
#pragma unroll
      for (int kc = 0; kc < 128; kc += 32) {
        bf16x8 bfr = *(const bf16x8*)&comb[nl][kc + quad * 8];
        of0 = __builtin_amdgcn_mfma_f32_16x16x32_bf16(*(const bf16x8*)(a0p + kc), bfr, of0, 0, 0, 0);
        of1 = __builtin_amdgcn_mfma_f32_16x16x32_bf16(*(const bf16x8*)(a1p + kc), bfr, of1, 0, 0, 0);
      }
#pragma unroll
      for (int t = 0; t < 2; ++t) {
        f32x4 acc = t ? of1 : of0;
        if (seg == 0) {
          bf16x4 pk;
#pragma unroll
          for (int reg = 0; reg < 4; ++reg)
            pk[reg] = (__bf16)((acc[reg] + pq_b[ol0 + t * 16 + quad * 4 + reg]) * qscale);
          *(bf16x4*)(Qt + ((size_t)b * NSP + n) * 128 + ol0 + t * 16 + quad * 4) = pk;
        } else if (seg == 1) {
          bf16x4 pk;
#pragma unroll
          for (int reg = 0; reg < 4; ++reg)
            pk[reg] = (__bf16)(acc[reg] + k_b[ol0 + t * 16 + quad * 4 + reg]);
          *(bf16x4*)(K2t + ((size_t)b * NSP + n) * 128 + ol0 + t * 16 + quad * 4) = pk;
        } else {
#pragma unroll
          for (int reg = 0; reg < 4; ++reg) {
            int ol = ol0 + t * 16 + quad * 4 + reg;
            V2b[((size_t)b * 128 + ol) * NSP + n] = (__bf16)(acc[reg] + v_b[ol]);
          }
        }
      }
    }
  }
}

// ---------------- fused combine128 + FFN: x1 kept in LDS, out written directly ----------------
__global__ __launch_bounds__(256) void c128ffn_kernel(
    const __bf16* __restrict__ Op, const float* __restrict__ lp,
    const float* __restrict__ x, const __bf16* __restrict__ wfc1,
    const float* __restrict__ fc1_b, const __bf16* __restrict__ wfc2,
    const float* __restrict__ fc2_b, float* __restrict__ outp) {
  __shared__ float x1f[16][132];
  __shared__ __bf16 x1l[16][136];
  __shared__ __bf16 hl[16][520];
  int tid = threadIdx.x;
  int b = blockIdx.y;
  int n0 = blockIdx.x * 16;
  {
    int r = tid & 15, g = tid >> 4;
    float ltot = 0.f;
#pragma unroll
    for (int ks = 0; ks < KS; ++ks) ltot += lp[(size_t)(ks * BB + b) * NSP + n0 + r];
    float linv = 1.0f / ltot;
#pragma unroll
    for (int j = 0; j < 8; ++j) {
      int ch = g * 8 + j;
      float s = 0.f;
#pragma unroll
      for (int ks = 0; ks < KS; ++ks)
        s += (float)Op[((size_t)(ks * BB + b) * CC + ch) * NSP + n0 + r];
      float v = s * linv + x[((size_t)b * CC + ch) * NSP + n0 + r];
      x1f[r][ch] = v;
      x1l[r][ch] = (__bf16)v;
    }
  }
  __syncthreads();
  int wv = tid >> 6, lane = tid & 63;
  int m15 = lane & 15, quad = lane >> 4;
  bf16x8 bf[4];
#pragma unroll
  for (int kc = 0; kc < 4; ++kc) bf[kc] = *(const bf16x8*)&x1l[m15][kc * 32 + quad * 8];
#pragma unroll
  for (int j = 0; j < 4; ++j) {
    int o0 = (wv * 4 + j) * 32;
    const __bf16* a0p = wfc1 + (size_t)(o0 + m15) * 128 + quad * 8;
    const __bf16* a1p = wfc1 + (size_t)(o0 + 16 + m15) * 128 + quad * 8;
    f32x4 of0 = (f32x4){0.f, 0.f, 0.f, 0.f};
    f32x4 of1 = (f32x4){0.f, 0.f, 0.f, 0.f};
#pragma unroll
    for (int kc = 0; kc < 4; ++kc) {
      of0 = __builtin_amdgcn_mfma_f32_16x16x32_bf16(*(const bf16x8*)(a0p + kc * 32), bf[kc], of0, 0, 0, 0);
      of1 = __builtin_amdgcn_mfma_f32_16x16x32_bf16(*(const bf16x8*)(a1p + kc * 32), bf[kc], of1, 0, 0, 0);
    }
#pragma unroll
    for (int t = 0; t < 2; ++t) {
      f32x4 acc = t ? of1 : of0;
      bf16x4 pk;
#pragma unroll
      for (int reg = 0; reg < 4; ++reg) {
        float v = fmaxf(acc[reg] + fc1_b[o0 + t * 16 + quad * 4 + reg], 0.0f);
        pk[reg] = (__bf16)(v * v);
      }
      *(bf16x4*)&hl[m15][o0 + t * 16 + quad * 4] = pk;
    }
  }
  __syncthreads();
  int o0 = wv * 32;
  const __bf16* a0p = wfc2 + (size_t)(o0 + m15) * 512 + quad * 8;
  const __bf16* a1p = wfc2 + (size_t)(o0 + 16 + m15) * 512 + quad * 8;
  f32x4 of0 = (f32x4){0.f, 0.f, 0.f, 0.f};
  f32x4 of1 = (f32x4){0.f, 0.f, 0.f, 0.f};
#pragma unroll
  for (int kc = 0; kc < 512; kc += 32) {
    bf16x8 bfr = *(const bf16x8*)&hl[m15][kc + quad * 8];
    of0 = __builtin_amdgcn_mfma_f32_16x16x32_bf16(*(const bf16x8*)(a0p + kc), bfr, of0, 0, 0, 0);
    of1 = __builtin_amdgcn_mfma_f32_16x16x32_bf16(*(const bf16x8*)(a1p + kc), bfr, of1, 0, 0, 0);
  }
  int n = n0 + m15;
#pragma unroll
  for (int t = 0; t < 2; ++t) {
    f32x4 acc = t ? of1 : of0;
#pragma unroll
    for (int reg = 0; reg < 4; ++reg) {
      int ol = o0 + t * 16 + quad * 4 + reg;
      outp[((size_t)b * 128 + ol) * NSP + n] = acc[reg] + fc2_b[ol] + x1f[m15][ol];
    }
  }
}

// ---------------- host ----------------
extern "C" void kernel_launch(void* const* d_in, const int* in_sizes, int n_in,
                              void* d_out, int out_size, void* d_ws, size_t ws_size,
                              hipStream_t stream) {
  const float* x = (const float*)d_in[0];
  const float* r_w = (const float*)d_in[1];
  const float* r_b = (const float*)d_in[2];
  const float* k_w = (const float*)d_in[3];
  const float* k_b = (const float*)d_in[4];
  const float* v_w = (const float*)d_in[5];
  const float* v_b = (const float*)d_in[6];
  // d_in[7..10]: wc1/wc2 — dead code (multiplied by zeros in reference)
  const float* u = (const float*)d_in[11];
  const float* sn1_w = (const float*)d_in[12];
  const float* sn1_b = (const float*)d_in[13];
  const float* sn2_w = (const float*)d_in[14];
  const float* sn2_b = (const float*)d_in[15];
  const float* lb_w = (const float*)d_in[16];
  const float* lb_b = (const float*)d_in[17];
  const float* ld_w = (const float*)d_in[18];
  const float* ld_b = (const float*)d_in[19];
  const float* ps_w = (const float*)d_in[20];
  const float* ps_b = (const float*)d_in[21];
  const float* pq_w = (const float*)d_in[22];
  const float* pq_b = (const float*)d_in[23];
  const float* fc1_w = (const float*)d_in[24];
  const float* fc1_b = (const float*)d_in[25];
  const float* fc2_w = (const float*)d_in[26];
  const float* fc2_b = (const float*)d_in[27];
  const float* db_g[4] = {(const float*)d_in[28], (const float*)d_in[32],
                          (const float*)d_in[36], (const float*)d_in[40]};
  const float* db_b[4] = {(const float*)d_in[29], (const float*)d_in[33],
                          (const float*)d_in[37], (const float*)d_in[41]};
  const float* db_w[4] = {(const float*)d_in[30], (const float*)d_in[34],
                          (const float*)d_in[38], (const float*)d_in[42]};
  const float* db_cb[4] = {(const float*)d_in[31], (const float*)d_in[35],
                           (const float*)d_in[39], (const float*)d_in[43]};

  float* outp = (float*)d_out;           // out  (B,C,H,W)
  float* knum = outp + BCN;              // new_num = k*v
  float* kden = outp + 2 * (size_t)BCN;  // new_den = k

  float* ws = (float*)d_ws;
  // region map (f32 slots)
  const size_t F_FEATS = 0;         // cpart0/1/2 -> Op partials (KS=4 CD=128 = 2359296)
  const size_t F_REC = 4718592;     // rec f32 (1179648)
  const size_t F_V = 5898240;       // V2b bf16 (589824)
  const size_t F_R = 7077888;       // dense_t bf16 (589824)
  const size_t F_XR = 8257536;      // xrope_t bf16 -> Qt (589824)
  const size_t F_XT = 8847360;      // x_t bf16 -> K2t (589824)
  const size_t F_DFB = 9437184;     // Dfb bf16 (147456)
  const size_t F_CT = 9732096;      // Bft (upper half)
  const size_t F_LP = 10321920;     // lp f32 (KS*B*NSP = 36864)
  const size_t F_WB = 10434048;     // conv1x1 weights bf16 (282624 bf16 = 141312 slots)
  const size_t F_WB3 = 10575360;    // conv3x3 packed weights bf16 (202752 bf16 = 101376 slots)
  const size_t F_STATS = 10676736;  // sums[256] sums2[256]
  const size_t F_TAUP = 10714112;   // tau partials (1024 x 144 = 147456)
  float* sums = ws + F_STATS;
  float* sums2 = ws + F_STATS + 256;
  float* cpart0 = ws + F_FEATS;        // conv stat partials, per layer (64 x 576 each)
  float* cpart1 = cpart0 + 36864;
  float* cpart2 = cpart1 + 36864;
  float* taupart = ws + F_TAUP;
  float* lp = ws + F_LP;
  __bf16* wbase = (__bf16*)(ws + F_WB);
  __bf16* wb3 = (__bf16*)(ws + F_WB3);
  const int W_KV = 0;        // k(16384) | v(16384)
  const int W_R = 32768;     // 16384
  const int W_SN1 = 49152;   // 16384
  const int W_SN2 = 65536;   // 16384
  const int W_LBLD = 81920;  // lb(8192) | ld(8192)
  const int W_PS = 98304;    // 4096
  const int W_PQK = 102400;  // pq(16384) | k(16384) | v(16384)
  const int W_FC1 = 151552;  // 65536
  const int W_FC2 = 217088;  // 65536
  const int W3_OFF[4] = {0, 36864, 82944, 138240};

  dim3 blk(256);
  __bf16* xrope_t = (__bf16*)(ws + F_XR);
  __bf16* x_t = (__bf16*)(ws + F_XT);

  // --- prep: weight cvt + conv pack + x stats + x dual-transpose, ONE launch ---
  Prep pp;
  pp.wsrc[0] = k_w;    pp.wlen[0] = 16384; pp.woff[0] = W_KV;
  pp.wsrc[1] = v_w;    pp.wlen[1] = 16384; pp.woff[1] = W_KV + 16384;
  pp.wsrc[2] = r_w;    pp.wlen[2] = 16384; pp.woff[2] = W_R;
  pp.wsrc[3] = sn1_w;  pp.wlen[3] = 16384; pp.woff[3] = W_SN1;
  pp.wsrc[4] = sn2_w;  pp.wlen[4] = 16384; pp.woff[4] = W_SN2;
  pp.wsrc[5] = lb_w;   pp.wlen[5] = 8192;  pp.woff[5] = W_LBLD;
  pp.wsrc[6] = ld_w;   pp.wlen[6] = 8192;  pp.woff[6] = W_LBLD + 8192;
  pp.wsrc[7] = ps_w;   pp.wlen[7] = 4096;  pp.woff[7] = W_PS;
  pp.wsrc[8] = pq_w;   pp.wlen[8] = 16384; pp.woff[8] = W_PQK;
  pp.wsrc[9] = k_w;    pp.wlen[9] = 16384; pp.woff[9] = W_PQK + 16384;
  pp.wsrc[10] = v_w;   pp.wlen[10] = 16384; pp.woff[10] = W_PQK + 32768;
  pp.wsrc[11] = fc1_w; pp.wlen[11] = 65536; pp.woff[11] = W_FC1;
  pp.wsrc[12] = fc2_w; pp.wlen[12] = 65536; pp.woff[12] = W_FC2;
  for (int i = 0; i < 4; ++i) {
    pp.psrc[i] = db_w[i];
    pp.pcin[i] = 128 + 32 * i;
    pp.poff[i] = W3_OFF[i];
  }
  pp.x = x;
  pp.sums = sums;
  pp.sums2 = sums2;
  pp.x_t = x_t;
  pp.xrope_t = xrope_t;
  prep_kernel<<<dim3(256, 23), blk, 0, stream>>>(pp, wbase, wb3);

  // --- conv layer 0 + kvr in ONE launch (independent; co-scheduled via blockIdx.z) ---
  __bf16* dense_t = (__bf16*)(ws + F_R);
  conv128kvr_kernel<<<dim3(144, 4, 2), blk, 0, stream>>>(
      x_t, xrope_t, wb3 + W3_OFF[0], db_cb[0], sums, sums2, db_g[0], db_b[0],
      dense_t, cpart0,
      wbase + W_KV, wbase + W_KV + 16384, wbase + W_R,
      k_b, v_b, r_b, u, kden, knum, ws + F_REC);

  // --- dense block layers 1-3 ---
  convbn_kernel<160><<<dim3(144, 4), blk, 0, stream>>>(
      x_t, dense_t, wb3 + W3_OFF[1], db_cb[1], sums, sums2, cpart0,
      db_g[1], db_b[1], dense_t, cpart1, 160);
  convbn_kernel<192><<<dim3(144, 4), blk, 0, stream>>>(
      x_t, dense_t, wb3 + W3_OFF[2], db_cb[2], sums, sums2, cpart1,
      db_g[2], db_b[2], dense_t, cpart2, 192);
  convbn_kernel<224><<<dim3(144, 4), blk, 0, stream>>>(
      x_t, dense_t, wb3 + W3_OFF[3], db_cb[3], sums, sums2, cpart2,
      db_g[3], db_b[3], dense_t, nullptr, 224);

  // --- spike path: fused sn1+sn2 (tau partials), sf inline in lb/ld GEMM ---
  sn12_kernel<<<dim3(144, 4), blk, 0, stream>>>(
      x_t, dense_t, wbase + W_SN1, sn1_b, wbase + W_SN2, sn2_b, taupart);
  __bf16* Bft = (__bf16*)(ws + F_CT + 294912);  // upper half of F_CT region
  __bf16* Dfb = (__bf16*)(ws + F_DFB);
  lbld_sf_kernel<<<dim3(144, 4), dim3(128), 0, stream>>>(
      x_t, dense_t, taupart, wbase + W_LBLD, lb_b, ld_b, Bft, Dfb);
  __bf16* Opart = (__bf16*)(ws + F_FEATS);  // cpart dead from here
  attn_part_kernel<32><<<dim3(36, 4, KS), blk, 0, stream>>>(Bft, Bft, Dfb, Opart, lp);

  // --- fused combine32+ps+QKV (comb never hits memory) ---
  __bf16* Qt = (__bf16*)(ws + F_XR);   // xrope_t dead after kvr
  __bf16* K2t = (__bf16*)(ws + F_XT);  // x_t dead after lbld_sf
  __bf16* V2b = (__bf16*)(ws + F_V);
  c32psqkv_kernel<<<dim3(72, 4), blk, 0, stream>>>(
      Opart, lp, wbase + W_PS, ps_b, ws + F_REC, wbase + W_PQK,
      pq_b, k_b, v_b, Qt, K2t, V2b, 0.08838834764831845f);

  // --- final attention + fused combine128+FFN (x1/x1_t/h never hit memory) ---
  attn_part_kernel<128><<<dim3(36, 4, KS), blk, 0, stream>>>(Qt, K2t, V2b, Opart, lp);
  c128ffn_kernel<<<dim3(144, 4), blk, 0, stream>>>(
      Opart, lp, x, wbase + W_FC1, fc1_b, wbase + W_FC2, fc2_b, outp);
}